// Round 2
// baseline (2508.154 us; speedup 1.0000x reference)
//
#include <hip/hip_runtime.h>
#include <hip/hip_bf16.h>
#include <math.h>

#define D_MODEL   1024
#define D_STATE   128
#define HEADDIM   64
#define CHUNK     64
#define D_INNER   2048
#define NHEADS    32
#define D_IN_PROJ 4384   // 2*2048 + 2*128 + 32
#define CONV_CH   2304   // 2048 + 256
#define RCOLS     2336   // CONV_CH + NHEADS (xBC-raw + dt-raw columns)
#define BATCH     2
#define SEQ       4096
#define NCHUNK    64     // SEQ / CHUNK
#define ROWS      (BATCH*SEQ)   // 8192
#define EPS_RMS   1e-5f

typedef __hip_bfloat16 bf16;

__device__ __forceinline__ float siluf_(float x){ return x/(1.f+expf(-x)); }
__device__ __forceinline__ float ldf(const float* p){ return *p; }
__device__ __forceinline__ float ldf(const bf16* p){ return __bfloat162float(*p); }
__device__ __forceinline__ void  stf(float* p, float v){ *p = v; }
__device__ __forceinline__ void  stf(bf16* p, float v){ *p = __float2bfloat16(v); }

// ---------------------------------------------------------------------------
// Generic GEMM: C[M,N] = A[M,K] @ B[K,N]. Row-major, fp32 accumulate.
// A: fp32 or bf16; B: fp32; C: fp32 or bf16 (leading dims lda/ldb/ldc).
// 128x128 tile, BK=8, 256 threads, 8x8 micro-tile per thread. M%128==0, K%8==0.
// ---------------------------------------------------------------------------
template <typename TA, typename TC>
__global__ __launch_bounds__(256) void gemm_tpl(const TA* __restrict__ A, int lda,
                                                const float* __restrict__ B, int ldb,
                                                TC* __restrict__ C, int ldc,
                                                int M, int N, int K) {
    __shared__ float As[8 * 132];   // transposed A tile, padded
    __shared__ float Bs[8 * 128];
    const int tid = threadIdx.x;
    const int tx = tid & 15, ty = tid >> 4;
    const int row0 = blockIdx.y * 128, col0 = blockIdx.x * 128;
    float acc[8][8];
#pragma unroll
    for (int i = 0; i < 8; ++i)
#pragma unroll
        for (int j = 0; j < 8; ++j) acc[i][j] = 0.f;

    for (int kk = 0; kk < K; kk += 8) {
#pragma unroll
        for (int i = 0; i < 4; ++i) {
            int idx = tid + i * 256;        // 0..1023
            int m = idx >> 3, k = idx & 7;  // A tile 128 x 8
            As[k * 132 + m] = ldf(&A[(size_t)(row0 + m) * lda + kk + k]);
        }
#pragma unroll
        for (int i = 0; i < 4; ++i) {
            int idx = tid + i * 256;
            int k = idx >> 7, n = idx & 127; // B tile 8 x 128
            int gn = col0 + n;
            Bs[k * 128 + n] = (gn < N) ? B[(size_t)(kk + k) * ldb + gn] : 0.f;
        }
        __syncthreads();
#pragma unroll
        for (int k = 0; k < 8; ++k) {
            float a[8], b[8];
#pragma unroll
            for (int i = 0; i < 8; ++i) a[i] = As[k * 132 + ty * 8 + i];
#pragma unroll
            for (int j = 0; j < 8; ++j) b[j] = Bs[k * 128 + tx * 8 + j];
#pragma unroll
            for (int i = 0; i < 8; ++i)
#pragma unroll
                for (int j = 0; j < 8; ++j) acc[i][j] += a[i] * b[j];
        }
        __syncthreads();
    }
#pragma unroll
    for (int i = 0; i < 8; ++i) {
        int gm = row0 + ty * 8 + i;
#pragma unroll
        for (int j = 0; j < 8; ++j) {
            int gn = col0 + tx * 8 + j;
            if (gn < N) stf(&C[(size_t)gm * ldc + gn], acc[i][j]);
        }
    }
}

// ---------------------------------------------------------------------------
// Depthwise causal conv (k=4) + bias + SiLU. R holds raw xBC (bf16, ld RCOLS).
// ---------------------------------------------------------------------------
__global__ void conv_silu_kernel(const bf16* __restrict__ R,
                                 const float* __restrict__ conv_w,
                                 const float* __restrict__ conv_b,
                                 bf16* __restrict__ xBC) {
    int ch = blockIdx.x * 256 + threadIdx.x;
    int row = blockIdx.y;
    if (ch >= CONV_CH) return;
    int l = row & (SEQ - 1);
    int b = row >> 12;              // SEQ = 4096
    float acc = conv_b[ch];
#pragma unroll
    for (int k = 0; k < 4; ++k) {
        int ls = l - 3 + k;
        if (ls >= 0)
            acc += conv_w[ch * 4 + k] *
                   ldf(&R[(size_t)(b * SEQ + ls) * RCOLS + ch]);
    }
    stf(&xBC[(size_t)row * CONV_CH + ch], siluf_(acc));
}

// dt[row][h] = softplus(R[row][CONV_CH+h] + dt_bias[h])   (fp32 out)
__global__ void dt_kernel(const bf16* __restrict__ R,
                          const float* __restrict__ dt_bias,
                          float* __restrict__ dtb) {
    int i = blockIdx.x * 256 + threadIdx.x;
    if (i >= ROWS * NHEADS) return;
    int row = i >> 5, h = i & 31;
    float v = ldf(&R[(size_t)row * RCOLS + CONV_CH + h]) + dt_bias[h];
    dtb[i] = (v > 20.f) ? v : log1pf(expf(v));
}

// Per (b,c,h): inclusive cumsum of A[h]*dt over the 64-long chunk. (fp32)
__global__ void acum_kernel(const float* __restrict__ dtb,
                            const float* __restrict__ A_log,
                            float* __restrict__ Acum) {
    int bch = blockIdx.x;                // ((b*64+c)*32+h)
    int h = bch & 31;
    int bc = bch >> 5;
    int c = bc & 63, b = bc >> 6;
    int row0 = b * SEQ + c * CHUNK;
    __shared__ float sh[64];
    int l = threadIdx.x;
    float Ah = -expf(A_log[h]);
    sh[l] = Ah * dtb[(size_t)(row0 + l) * NHEADS + h];
    __syncthreads();
    float s = 0.f;
    for (int j = 0; j <= l; ++j) s += sh[j];
    Acum[(size_t)bch * 64 + l] = s;
}

// Per (b,c): G[l][s] = sum_n C[l,n]*B[s,n]   (head independent, fp32 out)
__global__ __launch_bounds__(256) void gchunk_kernel(const bf16* __restrict__ xBC,
                                                     float* __restrict__ Gbuf) {
    int bc = blockIdx.x;
    int c = bc & 63, b = bc >> 6;
    int row0 = b * SEQ + c * CHUNK;
    __shared__ float Bs[64 * 129];
    int tid = threadIdx.x;
    for (int i = tid; i < 64 * 128; i += 256) {
        int l = i >> 7, n = i & 127;
        Bs[l * 129 + n] = ldf(&xBC[(size_t)(row0 + l) * CONV_CH + D_INNER + n]);
    }
    __syncthreads();
    for (int i = tid; i < 64 * 64; i += 256) {
        int l = i >> 6, s = i & 63;
        const bf16* Crow = xBC + (size_t)(row0 + l) * CONV_CH + D_INNER + D_STATE;
        float acc = 0.f;
#pragma unroll 8
        for (int n = 0; n < 128; ++n) acc += ldf(&Crow[n]) * Bs[s * 129 + n];
        Gbuf[(size_t)bc * 4096 + i] = acc;
    }
}

// Per (b,c,h): states[p][n] = sum_l B[l,n] * exp(Ac[63]-Ac[l]) * x[l,p]*dt[l]
__global__ __launch_bounds__(256) void states_kernel(const bf16* __restrict__ xBC,
                                                     const float* __restrict__ dtb,
                                                     const float* __restrict__ Acum,
                                                     bf16* __restrict__ states) {
    int bch = blockIdx.x;
    int h = bch & 31;
    int bc = bch >> 5;
    int c = bc & 63, b = bc >> 6;
    int row0 = b * SEQ + c * CHUNK;
    __shared__ float Bs[64 * 128];
    __shared__ float xs[64 * 64];
    __shared__ float dec[64];
    int tid = threadIdx.x;
    for (int i = tid; i < 64 * 128; i += 256) {
        int l = i >> 7, n = i & 127;
        Bs[i] = ldf(&xBC[(size_t)(row0 + l) * CONV_CH + D_INNER + n]);
    }
    for (int i = tid; i < 64 * 64; i += 256) {
        int l = i >> 6, p = i & 63;
        xs[i] = ldf(&xBC[(size_t)(row0 + l) * CONV_CH + h * 64 + p]) *
                dtb[(size_t)(row0 + l) * NHEADS + h];
    }
    if (tid < 64) {
        float alast = Acum[(size_t)bch * 64 + 63];
        dec[tid] = expf(alast - Acum[(size_t)bch * 64 + tid]);
    }
    __syncthreads();
    int p = tid & 63, ng = tid >> 6;   // 4 groups of 32 n
    float acc[32];
#pragma unroll
    for (int j = 0; j < 32; ++j) acc[j] = 0.f;
    for (int l = 0; l < 64; ++l) {
        float f = xs[l * 64 + p] * dec[l];
#pragma unroll
        for (int j = 0; j < 32; ++j) acc[j] += f * Bs[l * 128 + ng * 32 + j];
    }
    size_t base = (size_t)bch * 8192 + (size_t)p * 128 + ng * 32;
#pragma unroll
    for (int j = 0; j < 32; ++j) stf(&states[base + j], acc[j]);
}

// Inter-chunk scan (in place): states[b,c,h,p,n] becomes the state ENTERING
// chunk c.  carry' = exp(A_last[c]) * carry + S[c].  Carry kept fp32.
__global__ void scan_kernel(const float* __restrict__ Acum,
                            bf16* __restrict__ states) {
    int i = blockIdx.x * 256 + threadIdx.x;
    int pn = i & 8191;
    int bh = i >> 13;
    int h = bh & 31, b = bh >> 5;
    float carry = 0.f;
    for (int c = 0; c < NCHUNK; ++c) {
        int bch = (b * NCHUNK + c) * NHEADS + h;
        size_t idx = (size_t)bch * 8192 + pn;
        float s = ldf(&states[idx]);
        stf(&states[idx], carry);
        carry = carry * expf(Acum[(size_t)bch * 64 + 63]) + s;
    }
}

// Per (b,c,h): Y_diag[l,p] = sum_{s<=l} G[l,s]*exp(ac[l]-ac[s])*dt[s]*x[s,p]
//              + x[l,p]*D[h]   -> write y (bf16)
__global__ __launch_bounds__(256) void ydiag_kernel(const bf16* __restrict__ xBC,
                                                    const float* __restrict__ dtb,
                                                    const float* __restrict__ Acum,
                                                    const float* __restrict__ Gbuf,
                                                    const float* __restrict__ Dv,
                                                    bf16* __restrict__ y) {
    int bch = blockIdx.x;
    int h = bch & 31;
    int bc = bch >> 5;
    int c = bc & 63, b = bc >> 6;
    int row0 = b * SEQ + c * CHUNK;
    __shared__ float Gs[64 * 65];
    __shared__ float xs[64 * 64];
    __shared__ float ac[64], dts[64];
    int tid = threadIdx.x;
    for (int i = tid; i < 64 * 64; i += 256) {
        int l = i >> 6, s = i & 63;
        Gs[l * 65 + s] = Gbuf[(size_t)bc * 4096 + i];
    }
    for (int i = tid; i < 64 * 64; i += 256) {
        int l = i >> 6, p = i & 63;
        xs[i] = ldf(&xBC[(size_t)(row0 + l) * CONV_CH + h * 64 + p]);
    }
    if (tid < 64) {
        ac[tid] = Acum[(size_t)bch * 64 + tid];
        dts[tid] = dtb[(size_t)(row0 + tid) * NHEADS + h];
    }
    __syncthreads();
    int l = tid & 63, pg = tid >> 6;   // thread owns row l, 16 p's
    float Dh = Dv[h];
    float acl = ac[l];
    float acc[16];
#pragma unroll
    for (int j = 0; j < 16; ++j) acc[j] = 0.f;
    for (int s = 0; s <= l; ++s) {
        float coef = Gs[l * 65 + s] * expf(acl - ac[s]) * dts[s];
#pragma unroll
        for (int j = 0; j < 16; ++j) acc[j] += coef * xs[s * 64 + pg * 16 + j];
    }
#pragma unroll
    for (int j = 0; j < 16; ++j) {
        int p = pg * 16 + j;
        stf(&y[(size_t)(row0 + l) * D_INNER + h * 64 + p],
            acc[j] + xs[l * 64 + p] * Dh);
    }
}

// Per (b,c,h): y[l,p] += exp(ac[l]) * sum_n C[l,n] * prev_state[p,n]
__global__ __launch_bounds__(256) void yoff_kernel(const bf16* __restrict__ xBC,
                                                   const float* __restrict__ Acum,
                                                   const bf16* __restrict__ states,
                                                   bf16* __restrict__ y) {
    int bch = blockIdx.x;
    int h = bch & 31;
    int bc = bch >> 5;
    int c = bc & 63, b = bc >> 6;
    int row0 = b * SEQ + c * CHUNK;
    __shared__ float prevs[64 * 129];   // [p][n] padded
    __shared__ float Cs[64 * 17];       // 16-wide n chunk of C, padded
    __shared__ float ac[64];
    int tid = threadIdx.x;
    for (int i = tid; i < 64 * 128; i += 256) {
        int p = i >> 7, n = i & 127;
        prevs[p * 129 + n] = ldf(&states[(size_t)bch * 8192 + i]);
    }
    if (tid < 64) ac[tid] = Acum[(size_t)bch * 64 + tid];
    __syncthreads();
    int p = tid & 63, lg = tid >> 6;    // thread owns col p, 16 l's
    float acc[16];
#pragma unroll
    for (int i = 0; i < 16; ++i) acc[i] = 0.f;
    for (int nb = 0; nb < 8; ++nb) {
        __syncthreads();
        for (int i = tid; i < 64 * 16; i += 256) {
            int l = i >> 4, nn = i & 15;
            Cs[l * 17 + nn] = ldf(&xBC[(size_t)(row0 + l) * CONV_CH + D_INNER +
                                       D_STATE + nb * 16 + nn]);
        }
        __syncthreads();
#pragma unroll
        for (int nn = 0; nn < 16; ++nn) {
            int n = nb * 16 + nn;
            float pv = prevs[p * 129 + n];
#pragma unroll
            for (int i = 0; i < 16; ++i)
                acc[i] += Cs[(lg * 16 + i) * 17 + nn] * pv;
        }
    }
#pragma unroll
    for (int i = 0; i < 16; ++i) {
        int l = lg * 16 + i;
        float sdo = expf(ac[l]);
        size_t idx = (size_t)(row0 + l) * D_INNER + h * 64 + p;
        stf(&y[idx], ldf(&y[idx]) + acc[i] * sdo);
    }
}

// Per row: v = y * silu(z); y = v * rsqrt(mean(v^2)+eps) * norm_w   (bf16 y/Z)
__global__ __launch_bounds__(256) void gate_norm_kernel(const bf16* __restrict__ Z,
                                                        const float* __restrict__ nw,
                                                        bf16* __restrict__ y) {
    int row = blockIdx.x;
    int tid = threadIdx.x;
    float vals[8];
    float local = 0.f;
#pragma unroll
    for (int i = 0; i < 8; ++i) {
        int col = tid + i * 256;
        float z = ldf(&Z[(size_t)row * D_INNER + col]);
        float v = ldf(&y[(size_t)row * D_INNER + col]) * siluf_(z);
        vals[i] = v;
        local += v * v;
    }
#pragma unroll
    for (int off = 32; off; off >>= 1) local += __shfl_down(local, off, 64);
    __shared__ float wsum[4];
    if ((tid & 63) == 0) wsum[tid >> 6] = local;
    __syncthreads();
    float total = wsum[0] + wsum[1] + wsum[2] + wsum[3];
    float scale = rsqrtf(total / (float)D_INNER + EPS_RMS);
#pragma unroll
    for (int i = 0; i < 8; ++i) {
        int col = tid + i * 256;
        stf(&y[(size_t)row * D_INNER + col], vals[i] * scale * nw[col]);
    }
}

// ---------------------------------------------------------------------------
extern "C" void kernel_launch(void* const* d_in, const int* in_sizes, int n_in,
                              void* d_out, int out_size, void* d_ws, size_t ws_size,
                              hipStream_t stream) {
    const float* u       = (const float*)d_in[0];
    const float* W_in    = (const float*)d_in[1];
    const float* conv_w  = (const float*)d_in[2];
    const float* conv_b  = (const float*)d_in[3];
    const float* dt_bias = (const float*)d_in[4];
    const float* A_log   = (const float*)d_in[5];
    const float* Dv      = (const float*)d_in[6];
    const float* norm_w  = (const float*)d_in[7];
    const float* W_out   = (const float*)d_in[8];
    float* out = (float*)d_out;

    // Workspace layout (bf16 intermediates, fp32 small stats). Total 168 MB.
    const size_t sz_xBC    = (size_t)ROWS * CONV_CH * 2;               // 37.75 MB
    const size_t sz_Z      = (size_t)ROWS * D_INNER * 2;               // 33.55 MB
    const size_t sz_y      = (size_t)ROWS * D_INNER * 2;               // 33.55 MB
    const size_t sz_states = (size_t)BATCH * NCHUNK * NHEADS * 8192 * 2; // 67.1 MB
    const size_t sz_dtb    = (size_t)ROWS * NHEADS * 4;                // 1 MB
    const size_t sz_Acum   = (size_t)BATCH * NCHUNK * NHEADS * 64 * 4; // 1 MB
    const size_t sz_Gbuf   = (size_t)BATCH * NCHUNK * 4096 * 4;        // 2 MB
    const size_t need = sz_xBC + sz_Z + sz_y + sz_states + sz_dtb + sz_Acum + sz_Gbuf;
    if (ws_size < need) {
        // Diagnostic fallback: clean absmax failure instead of a page fault.
        hipMemsetAsync(d_out, 0, (size_t)out_size * sizeof(float), stream);
        return;
    }
    char* ws = (char*)d_ws;
    size_t off = 0;
    bf16*  xBC    = (bf16*) (ws + off); off += sz_xBC;
    bf16*  Z      = (bf16*) (ws + off); off += sz_Z;
    bf16*  y      = (bf16*) (ws + off); off += sz_y;
    bf16*  states = (bf16*) (ws + off); off += sz_states;
    float* dtb    = (float*)(ws + off); off += sz_dtb;
    float* Acum   = (float*)(ws + off); off += sz_Acum;
    float* Gbuf   = (float*)(ws + off); off += sz_Gbuf;
    // R (raw xBC+dt GEMM1 cols) aliases the states region; R is dead before
    // states_kernel writes states.  sz_R = ROWS*RCOLS*2 = 38.3 MB <= 67.1 MB.
    bf16* R = states;

    // 1) GEMM1 split: Z = u @ W_in[:, :2048] ; R = u @ W_in[:, 2048:4384]
    gemm_tpl<float, bf16><<<dim3(D_INNER / 128, ROWS / 128), 256, 0, stream>>>(
        u, D_MODEL, W_in, D_IN_PROJ, Z, D_INNER, ROWS, D_INNER, D_MODEL);
    gemm_tpl<float, bf16><<<dim3((RCOLS + 127) / 128, ROWS / 128), 256, 0, stream>>>(
        u, D_MODEL, W_in + D_INNER, D_IN_PROJ, R, RCOLS, ROWS, RCOLS, D_MODEL);
    // 2) conv + silu -> xBC ; dt -> dtb
    conv_silu_kernel<<<dim3(9, ROWS), 256, 0, stream>>>(R, conv_w, conv_b, xBC);
    dt_kernel<<<(ROWS * NHEADS) / 256, 256, 0, stream>>>(R, dt_bias, dtb);
    // 3) per-chunk cumsum of A*dt
    acum_kernel<<<BATCH * NCHUNK * NHEADS, 64, 0, stream>>>(dtb, A_log, Acum);
    // 4) G = C @ B^T per (b,c)
    gchunk_kernel<<<BATCH * NCHUNK, 256, 0, stream>>>(xBC, Gbuf);
    // 5) per-chunk states (overwrites R region — R is dead now)
    states_kernel<<<BATCH * NCHUNK * NHEADS, 256, 0, stream>>>(xBC, dtb, Acum, states);
    // 6) inter-chunk scan (in place: states -> entering state)
    scan_kernel<<<(BATCH * NHEADS * HEADDIM * D_STATE) / 256, 256, 0, stream>>>(Acum, states);
    // 7) Y_diag + D*x -> y
    ydiag_kernel<<<BATCH * NCHUNK * NHEADS, 256, 0, stream>>>(xBC, dtb, Acum, Gbuf, Dv, y);
    // 8) Y_off += C @ prev_state * exp(ac)
    yoff_kernel<<<BATCH * NCHUNK * NHEADS, 256, 0, stream>>>(xBC, Acum, states, y);
    // 9) gate + RMSNorm (in place on y)
    gate_norm_kernel<<<ROWS, 256, 0, stream>>>(Z, norm_w, y);
    // 10) out = y @ W_out
    gemm_tpl<bf16, float><<<dim3(D_MODEL / 128, ROWS / 128), 256, 0, stream>>>(
        y, D_INNER, W_out, D_MODEL, out, D_MODEL, ROWS, D_MODEL, D_INNER);
}

// Round 4
// 796.585 us; speedup vs baseline: 3.1486x; 3.1486x over previous
//
#include <hip/hip_runtime.h>
#include <hip/hip_bf16.h>
#include <math.h>

#define D_MODEL   1024
#define D_STATE   128
#define HEADDIM   64
#define CHUNK     64
#define D_INNER   2048
#define NHEADS    32
#define D_IN_PROJ 4384   // 2*2048 + 2*128 + 32
#define CONV_CH   2304   // 2048 + 256
#define RCOLS     2336   // CONV_CH + NHEADS (xBC-raw + dt-raw columns)
#define WINT_ROWS 4480   // D_IN_PROJ padded so R-GEMM's 19th tile stays in-bounds
#define BATCH     2
#define SEQ       4096
#define NCHUNK    64     // SEQ / CHUNK
#define ROWS      (BATCH*SEQ)   // 8192
#define EPS_RMS   1e-5f

typedef __hip_bfloat16 bf16;
typedef __bf16 bf16x8_t __attribute__((ext_vector_type(8)));
typedef float  f32x4_t  __attribute__((ext_vector_type(4)));

__device__ __forceinline__ float siluf_(float x){ return x/(1.f+expf(-x)); }
__device__ __forceinline__ float ldf(const float* p){ return *p; }
__device__ __forceinline__ float ldf(const bf16* p){ return __bfloat162float(*p); }
__device__ __forceinline__ void  stf(float* p, float v){ *p = v; }
__device__ __forceinline__ void  stf(bf16* p, float v){ *p = __float2bfloat16(v); }

// async global->LDS, 16 B per lane; LDS dest is wave-uniform base + lane*16.
__device__ __forceinline__ void async16(const void* g, void* l) {
    __builtin_amdgcn_global_load_lds(
        (const __attribute__((address_space(1))) unsigned int*)g,
        (__attribute__((address_space(3))) unsigned int*)l, 16, 0, 0);
}

// ---------------------------------------------------------------------------
// MFMA GEMM: C[M,N] = A[M,K] @ Bt[N,K]^T.  A,Bt bf16 row-major (contiguous K),
// fp32 accumulate, C fp32 or bf16.  BM=BN=128, BK=32, 256 threads (4 waves),
// each wave owns a 64x64 output patch = 4x4 grid of 16x16x32 MFMA tiles.
// ONE mfma per (mi,ni) per BK=32: lane's 8 elems at k = (lane>>4)*8 span K=32.
// Requires M%128==0, K%32==0; N guarded on store; Bt must have at least
// ceil(N/128)*128 rows allocated (pad rows may hold garbage).
// ---------------------------------------------------------------------------
template <typename TC>
__global__ __launch_bounds__(256) void gemm_mfma_bt(const bf16* __restrict__ A, int lda,
                                                    const bf16* __restrict__ Bt, int ldb,
                                                    TC* __restrict__ C, int ldc,
                                                    int M, int N, int K) {
    __shared__ __align__(16) __bf16 As[128 * 32];
    __shared__ __align__(16) __bf16 Bs[128 * 32];
    const int tid  = threadIdx.x;
    const int wave = tid >> 6, lane = tid & 63;
    const int quad = lane >> 4, l16 = lane & 15;
    const int row0 = blockIdx.y * 128, col0 = blockIdx.x * 128;
    const int wr = (wave >> 1) * 64;   // wave's row offset in tile
    const int wc = (wave & 1) * 64;    // wave's col offset in tile

    f32x4_t acc[4][4];
#pragma unroll
    for (int i = 0; i < 4; ++i)
#pragma unroll
        for (int j = 0; j < 4; ++j) acc[i][j] = (f32x4_t){0.f, 0.f, 0.f, 0.f};

    // Staging: 8 chunks of 512 bf16 (16 rows x 32 cols) per matrix; wave w owns
    // chunks 2w, 2w+1. Lane covers row (lane>>2), cols (lane&3)*8..+7 of the
    // chunk; LDS slot base+lane*16B == row-major (lane>>2)*32+(lane&3)*8. 
    const int ca0 = wave * 2, ca1 = wave * 2 + 1;
    const int srow = lane >> 2, scol = (lane & 3) * 8;
    const bf16* Ag0 = A  + (size_t)(row0 + ca0 * 16 + srow) * lda + scol;
    const bf16* Ag1 = A  + (size_t)(row0 + ca1 * 16 + srow) * lda + scol;
    const bf16* Bg0 = Bt + (size_t)(col0 + ca0 * 16 + srow) * ldb + scol;
    const bf16* Bg1 = Bt + (size_t)(col0 + ca1 * 16 + srow) * ldb + scol;
    __bf16* Al0 = As + ca0 * 512;
    __bf16* Al1 = As + ca1 * 512;
    __bf16* Bl0 = Bs + ca0 * 512;
    __bf16* Bl1 = Bs + ca1 * 512;

    for (int kk = 0; kk < K; kk += 32) {
        async16(Ag0 + kk, Al0);
        async16(Ag1 + kk, Al1);
        async16(Bg0 + kk, Bl0);
        async16(Bg1 + kk, Bl1);
        __syncthreads();               // drains vmcnt -> LDS tile ready
        bf16x8_t af[4], bfr[4];
#pragma unroll
        for (int mi = 0; mi < 4; ++mi)
            af[mi] = *(const bf16x8_t*)(As + (wr + mi * 16 + l16) * 32 + quad * 8);
#pragma unroll
        for (int ni = 0; ni < 4; ++ni)
            bfr[ni] = *(const bf16x8_t*)(Bs + (wc + ni * 16 + l16) * 32 + quad * 8);
#pragma unroll
        for (int mi = 0; mi < 4; ++mi)
#pragma unroll
            for (int ni = 0; ni < 4; ++ni)
                acc[mi][ni] = __builtin_amdgcn_mfma_f32_16x16x32_bf16(
                    af[mi], bfr[ni], acc[mi][ni], 0, 0, 0);
        __syncthreads();               // all waves done reading before restage
    }

    // Epilogue: C/D layout col = lane&15, row = quad*4 + reg  [m89/m91].
#pragma unroll
    for (int ni = 0; ni < 4; ++ni) {
        int gc = col0 + wc + ni * 16 + l16;
        if (gc >= N) continue;
#pragma unroll
        for (int mi = 0; mi < 4; ++mi) {
#pragma unroll
            for (int r = 0; r < 4; ++r) {
                int gr = row0 + wr + mi * 16 + quad * 4 + r;
                stf(&C[(size_t)gr * ldc + gc], acc[mi][ni][r]);
            }
        }
    }
}

// fp32 -> bf16 cast, 4 elems/thread
__global__ void cvt_bf16_kernel(const float* __restrict__ src,
                                bf16* __restrict__ dst, int n4) {
    int i = blockIdx.x * 256 + threadIdx.x;
    if (i >= n4) return;
    float4 v = ((const float4*)src)[i];
    dst[i * 4 + 0] = __float2bfloat16(v.x);
    dst[i * 4 + 1] = __float2bfloat16(v.y);
    dst[i * 4 + 2] = __float2bfloat16(v.z);
    dst[i * 4 + 3] = __float2bfloat16(v.w);
}

// Wt[c][r] = W[r][c], fp32 -> bf16.  W is RxC; Wt is Cpad x R (pad rows = 0).
__global__ __launch_bounds__(256) void transpose_cvt_kernel(const float* __restrict__ W,
                                                            bf16* __restrict__ Wt,
                                                            int R, int C, int Cpad) {
    __shared__ float tile[32][33];
    int c0 = blockIdx.x * 32, r0 = blockIdx.y * 32;
    int tx = threadIdx.x & 31, ty = threadIdx.x >> 5;   // ty 0..7
    for (int i = ty; i < 32; i += 8) {
        int r = r0 + i, c = c0 + tx;
        tile[i][tx] = (c < C) ? W[(size_t)r * C + c] : 0.f;
    }
    __syncthreads();
    for (int i = ty; i < 32; i += 8) {
        int c = c0 + i, r = r0 + tx;
        stf(&Wt[(size_t)c * R + r], tile[tx][i]);
    }
}

// ---------------------------------------------------------------------------
// Depthwise causal conv (k=4) + bias + SiLU. R holds raw xBC (bf16, ld RCOLS).
// ---------------------------------------------------------------------------
__global__ void conv_silu_kernel(const bf16* __restrict__ R,
                                 const float* __restrict__ conv_w,
                                 const float* __restrict__ conv_b,
                                 bf16* __restrict__ xBC) {
    int ch = blockIdx.x * 256 + threadIdx.x;
    int row = blockIdx.y;
    if (ch >= CONV_CH) return;
    int l = row & (SEQ - 1);
    int b = row >> 12;              // SEQ = 4096
    float acc = conv_b[ch];
#pragma unroll
    for (int k = 0; k < 4; ++k) {
        int ls = l - 3 + k;
        if (ls >= 0)
            acc += conv_w[ch * 4 + k] *
                   ldf(&R[(size_t)(b * SEQ + ls) * RCOLS + ch]);
    }
    stf(&xBC[(size_t)row * CONV_CH + ch], siluf_(acc));
}

// dt[row][h] = softplus(R[row][CONV_CH+h] + dt_bias[h])   (fp32 out)
__global__ void dt_kernel(const bf16* __restrict__ R,
                          const float* __restrict__ dt_bias,
                          float* __restrict__ dtb) {
    int i = blockIdx.x * 256 + threadIdx.x;
    if (i >= ROWS * NHEADS) return;
    int row = i >> 5, h = i & 31;
    float v = ldf(&R[(size_t)row * RCOLS + CONV_CH + h]) + dt_bias[h];
    dtb[i] = (v > 20.f) ? v : log1pf(expf(v));
}

// Per (b,c,h): inclusive cumsum of A[h]*dt over the 64-long chunk. (fp32)
__global__ void acum_kernel(const float* __restrict__ dtb,
                            const float* __restrict__ A_log,
                            float* __restrict__ Acum) {
    int bch = blockIdx.x;                // ((b*64+c)*32+h)
    int h = bch & 31;
    int bc = bch >> 5;
    int c = bc & 63, b = bc >> 6;
    int row0 = b * SEQ + c * CHUNK;
    __shared__ float sh[64];
    int l = threadIdx.x;
    float Ah = -expf(A_log[h]);
    sh[l] = Ah * dtb[(size_t)(row0 + l) * NHEADS + h];
    __syncthreads();
    float s = 0.f;
    for (int j = 0; j <= l; ++j) s += sh[j];
    Acum[(size_t)bch * 64 + l] = s;
}

// Per (b,c): G[l][s] = sum_n C[l,n]*B[s,n]   (head independent, fp32 out)
__global__ __launch_bounds__(256) void gchunk_kernel(const bf16* __restrict__ xBC,
                                                     float* __restrict__ Gbuf) {
    int bc = blockIdx.x;
    int c = bc & 63, b = bc >> 6;
    int row0 = b * SEQ + c * CHUNK;
    __shared__ float Bs[64 * 129];
    int tid = threadIdx.x;
    for (int i = tid; i < 64 * 128; i += 256) {
        int l = i >> 7, n = i & 127;
        Bs[l * 129 + n] = ldf(&xBC[(size_t)(row0 + l) * CONV_CH + D_INNER + n]);
    }
    __syncthreads();
    for (int i = tid; i < 64 * 64; i += 256) {
        int l = i >> 6, s = i & 63;
        const bf16* Crow = xBC + (size_t)(row0 + l) * CONV_CH + D_INNER + D_STATE;
        float acc = 0.f;
#pragma unroll 8
        for (int n = 0; n < 128; ++n) acc += ldf(&Crow[n]) * Bs[s * 129 + n];
        Gbuf[(size_t)bc * 4096 + i] = acc;
    }
}

// Per (b,c,h): states[p][n] = sum_l B[l,n] * exp(Ac[63]-Ac[l]) * x[l,p]*dt[l]
__global__ __launch_bounds__(256) void states_kernel(const bf16* __restrict__ xBC,
                                                     const float* __restrict__ dtb,
                                                     const float* __restrict__ Acum,
                                                     bf16* __restrict__ states) {
    int bch = blockIdx.x;
    int h = bch & 31;
    int bc = bch >> 5;
    int c = bc & 63, b = bc >> 6;
    int row0 = b * SEQ + c * CHUNK;
    __shared__ float Bs[64 * 128];
    __shared__ float xs[64 * 64];
    __shared__ float dec[64];
    int tid = threadIdx.x;
    for (int i = tid; i < 64 * 128; i += 256) {
        int l = i >> 7, n = i & 127;
        Bs[i] = ldf(&xBC[(size_t)(row0 + l) * CONV_CH + D_INNER + n]);
    }
    for (int i = tid; i < 64 * 64; i += 256) {
        int l = i >> 6, p = i & 63;
        xs[i] = ldf(&xBC[(size_t)(row0 + l) * CONV_CH + h * 64 + p]) *
                dtb[(size_t)(row0 + l) * NHEADS + h];
    }
    if (tid < 64) {
        float alast = Acum[(size_t)bch * 64 + 63];
        dec[tid] = expf(alast - Acum[(size_t)bch * 64 + tid]);
    }
    __syncthreads();
    int p = tid & 63, ng = tid >> 6;   // 4 groups of 32 n
    float acc[32];
#pragma unroll
    for (int j = 0; j < 32; ++j) acc[j] = 0.f;
    for (int l = 0; l < 64; ++l) {
        float f = xs[l * 64 + p] * dec[l];
#pragma unroll
        for (int j = 0; j < 32; ++j) acc[j] += f * Bs[l * 128 + ng * 32 + j];
    }
    size_t base = (size_t)bch * 8192 + (size_t)p * 128 + ng * 32;
#pragma unroll
    for (int j = 0; j < 32; ++j) stf(&states[base + j], acc[j]);
}

// Inter-chunk scan (in place): states[b,c,h,p,n] becomes the state ENTERING
// chunk c.  carry' = exp(A_last[c]) * carry + S[c].  Carry kept fp32.
__global__ void scan_kernel(const float* __restrict__ Acum,
                            bf16* __restrict__ states) {
    int i = blockIdx.x * 256 + threadIdx.x;
    int pn = i & 8191;
    int bh = i >> 13;
    int h = bh & 31, b = bh >> 5;
    float carry = 0.f;
    for (int c = 0; c < NCHUNK; ++c) {
        int bch = (b * NCHUNK + c) * NHEADS + h;
        size_t idx = (size_t)bch * 8192 + pn;
        float s = ldf(&states[idx]);
        stf(&states[idx], carry);
        carry = carry * expf(Acum[(size_t)bch * 64 + 63]) + s;
    }
}

// Per (b,c,h): Y_diag[l,p] = sum_{s<=l} G[l,s]*exp(ac[l]-ac[s])*dt[s]*x[s,p]
//              + x[l,p]*D[h]   -> write y (bf16)
__global__ __launch_bounds__(256) void ydiag_kernel(const bf16* __restrict__ xBC,
                                                    const float* __restrict__ dtb,
                                                    const float* __restrict__ Acum,
                                                    const float* __restrict__ Gbuf,
                                                    const float* __restrict__ Dv,
                                                    bf16* __restrict__ y) {
    int bch = blockIdx.x;
    int h = bch & 31;
    int bc = bch >> 5;
    int c = bc & 63, b = bc >> 6;
    int row0 = b * SEQ + c * CHUNK;
    __shared__ float Gs[64 * 65];
    __shared__ float xs[64 * 64];
    __shared__ float ac[64], dts[64];
    int tid = threadIdx.x;
    for (int i = tid; i < 64 * 64; i += 256) {
        int l = i >> 6, s = i & 63;
        Gs[l * 65 + s] = Gbuf[(size_t)bc * 4096 + i];
    }
    for (int i = tid; i < 64 * 64; i += 256) {
        int l = i >> 6, p = i & 63;
        xs[i] = ldf(&xBC[(size_t)(row0 + l) * CONV_CH + h * 64 + p]);
    }
    if (tid < 64) {
        ac[tid] = Acum[(size_t)bch * 64 + tid];
        dts[tid] = dtb[(size_t)(row0 + tid) * NHEADS + h];
    }
    __syncthreads();
    int l = tid & 63, pg = tid >> 6;   // thread owns row l, 16 p's
    float Dh = Dv[h];
    float acl = ac[l];
    float acc[16];
#pragma unroll
    for (int j = 0; j < 16; ++j) acc[j] = 0.f;
    for (int s = 0; s <= l; ++s) {
        float coef = Gs[l * 65 + s] * expf(acl - ac[s]) * dts[s];
#pragma unroll
        for (int j = 0; j < 16; ++j) acc[j] += coef * xs[s * 64 + pg * 16 + j];
    }
#pragma unroll
    for (int j = 0; j < 16; ++j) {
        int p = pg * 16 + j;
        stf(&y[(size_t)(row0 + l) * D_INNER + h * 64 + p],
            acc[j] + xs[l * 64 + p] * Dh);
    }
}

// Per (b,c,h): y[l,p] += exp(ac[l]) * sum_n C[l,n] * prev_state[p,n]
__global__ __launch_bounds__(256) void yoff_kernel(const bf16* __restrict__ xBC,
                                                   const float* __restrict__ Acum,
                                                   const bf16* __restrict__ states,
                                                   bf16* __restrict__ y) {
    int bch = blockIdx.x;
    int h = bch & 31;
    int bc = bch >> 5;
    int c = bc & 63, b = bc >> 6;
    int row0 = b * SEQ + c * CHUNK;
    __shared__ float prevs[64 * 129];   // [p][n] padded
    __shared__ float Cs[64 * 17];       // 16-wide n chunk of C, padded
    __shared__ float ac[64];
    int tid = threadIdx.x;
    for (int i = tid; i < 64 * 128; i += 256) {
        int p = i >> 7, n = i & 127;
        prevs[p * 129 + n] = ldf(&states[(size_t)bch * 8192 + i]);
    }
    if (tid < 64) ac[tid] = Acum[(size_t)bch * 64 + tid];
    __syncthreads();
    int p = tid & 63, lg = tid >> 6;    // thread owns col p, 16 l's
    float acc[16];
#pragma unroll
    for (int i = 0; i < 16; ++i) acc[i] = 0.f;
    for (int nb = 0; nb < 8; ++nb) {
        __syncthreads();
        for (int i = tid; i < 64 * 16; i += 256) {
            int l = i >> 4, nn = i & 15;
            Cs[l * 17 + nn] = ldf(&xBC[(size_t)(row0 + l) * CONV_CH + D_INNER +
                                       D_STATE + nb * 16 + nn]);
        }
        __syncthreads();
#pragma unroll
        for (int nn = 0; nn < 16; ++nn) {
            int n = nb * 16 + nn;
            float pv = prevs[p * 129 + n];
#pragma unroll
            for (int i = 0; i < 16; ++i)
                acc[i] += Cs[(lg * 16 + i) * 17 + nn] * pv;
        }
    }
#pragma unroll
    for (int i = 0; i < 16; ++i) {
        int l = lg * 16 + i;
        float sdo = expf(ac[l]);
        size_t idx = (size_t)(row0 + l) * D_INNER + h * 64 + p;
        stf(&y[idx], ldf(&y[idx]) + acc[i] * sdo);
    }
}

// Per row: v = y * silu(z); y = v * rsqrt(mean(v^2)+eps) * norm_w   (bf16 y/Z)
__global__ __launch_bounds__(256) void gate_norm_kernel(const bf16* __restrict__ Z,
                                                        const float* __restrict__ nw,
                                                        bf16* __restrict__ y) {
    int row = blockIdx.x;
    int tid = threadIdx.x;
    float vals[8];
    float local = 0.f;
#pragma unroll
    for (int i = 0; i < 8; ++i) {
        int col = tid + i * 256;
        float z = ldf(&Z[(size_t)row * D_INNER + col]);
        float v = ldf(&y[(size_t)row * D_INNER + col]) * siluf_(z);
        vals[i] = v;
        local += v * v;
    }
#pragma unroll
    for (int off = 32; off; off >>= 1) local += __shfl_down(local, off, 64);
    __shared__ float wsum[4];
    if ((tid & 63) == 0) wsum[tid >> 6] = local;
    __syncthreads();
    float total = wsum[0] + wsum[1] + wsum[2] + wsum[3];
    float scale = rsqrtf(total / (float)D_INNER + EPS_RMS);
#pragma unroll
    for (int i = 0; i < 8; ++i) {
        int col = tid + i * 256;
        stf(&y[(size_t)row * D_INNER + col], vals[i] * scale * nw[col]);
    }
}

// ---------------------------------------------------------------------------
extern "C" void kernel_launch(void* const* d_in, const int* in_sizes, int n_in,
                              void* d_out, int out_size, void* d_ws, size_t ws_size,
                              hipStream_t stream) {
    const float* u       = (const float*)d_in[0];
    const float* W_in    = (const float*)d_in[1];
    const float* conv_w  = (const float*)d_in[2];
    const float* conv_b  = (const float*)d_in[3];
    const float* dt_bias = (const float*)d_in[4];
    const float* A_log   = (const float*)d_in[5];
    const float* Dv      = (const float*)d_in[6];
    const float* norm_w  = (const float*)d_in[7];
    const float* W_out   = (const float*)d_in[8];
    float* out = (float*)d_out;

    // Workspace layout (bf16 intermediates, fp32 small stats).
    const size_t sz_xBC    = (size_t)ROWS * CONV_CH * 2;                 // 37.7 MB
    const size_t sz_Z      = (size_t)ROWS * D_INNER * 2;                 // 33.6 MB
    const size_t sz_y      = (size_t)ROWS * D_INNER * 2;                 // 33.6 MB
    const size_t sz_states = (size_t)BATCH * NCHUNK * NHEADS * 8192 * 2; // 67.1 MB
    const size_t sz_dtb    = (size_t)ROWS * NHEADS * 4;                  // 1 MB
    const size_t sz_Acum   = (size_t)BATCH * NCHUNK * NHEADS * 64 * 4;   // 1 MB
    const size_t sz_Gbuf   = (size_t)BATCH * NCHUNK * 4096 * 4;          // 2 MB
    const size_t sz_WinT   = (size_t)WINT_ROWS * D_MODEL * 2;            // 9.2 MB
    const size_t sz_WoutT  = (size_t)D_MODEL * D_INNER * 2;              // 4.2 MB
    const size_t need = sz_xBC + sz_Z + sz_y + sz_states + sz_dtb + sz_Acum +
                        sz_Gbuf + sz_WinT + sz_WoutT;
    if (ws_size < need) {
        hipMemsetAsync(d_out, 0, (size_t)out_size * sizeof(float), stream);
        return;
    }
    char* ws = (char*)d_ws;
    size_t off = 0;
    bf16*  xBC    = (bf16*) (ws + off); off += sz_xBC;
    bf16*  Z      = (bf16*) (ws + off); off += sz_Z;
    bf16*  y      = (bf16*) (ws + off); off += sz_y;
    bf16*  states = (bf16*) (ws + off); off += sz_states;
    float* dtb    = (float*)(ws + off); off += sz_dtb;
    float* Acum   = (float*)(ws + off); off += sz_Acum;
    float* Gbuf   = (float*)(ws + off); off += sz_Gbuf;
    bf16*  W_inT  = (bf16*) (ws + off); off += sz_WinT;
    bf16*  W_outT = (bf16*) (ws + off); off += sz_WoutT;
    // R (raw GEMM1 xBC+dt cols, 38.3 MB) and u_bf16 (16.8 MB) alias the states
    // region (67.1 MB) — both are dead before states_kernel writes it.
    bf16* R      = states;
    bf16* u_bf16 = (bf16*)((char*)states + (size_t)ROWS * RCOLS * 2);

    // 0) prep: u -> bf16; W_in, W_out -> transposed bf16 (contiguous K)
    cvt_bf16_kernel<<<(ROWS * D_MODEL / 4 + 255) / 256, 256, 0, stream>>>(
        u, u_bf16, ROWS * D_MODEL / 4);
    transpose_cvt_kernel<<<dim3(WINT_ROWS / 32, D_MODEL / 32), 256, 0, stream>>>(
        W_in, W_inT, D_MODEL, D_IN_PROJ, WINT_ROWS);
    transpose_cvt_kernel<<<dim3(D_MODEL / 32, D_INNER / 32), 256, 0, stream>>>(
        W_out, W_outT, D_INNER, D_MODEL, D_MODEL);

    // 1) GEMM1 split: Z = u @ W_in[:, :2048] ; R = u @ W_in[:, 2048:4384]
    gemm_mfma_bt<bf16><<<dim3(D_INNER / 128, ROWS / 128), 256, 0, stream>>>(
        u_bf16, D_MODEL, W_inT, D_MODEL, Z, D_INNER, ROWS, D_INNER, D_MODEL);
    gemm_mfma_bt<bf16><<<dim3((RCOLS + 127) / 128, ROWS / 128), 256, 0, stream>>>(
        u_bf16, D_MODEL, W_inT + (size_t)D_INNER * D_MODEL, D_MODEL,
        R, RCOLS, ROWS, RCOLS, D_MODEL);
    // 2) conv + silu -> xBC ; dt -> dtb
    conv_silu_kernel<<<dim3(9, ROWS), 256, 0, stream>>>(R, conv_w, conv_b, xBC);
    dt_kernel<<<(ROWS * NHEADS) / 256, 256, 0, stream>>>(R, dt_bias, dtb);
    // 3) per-chunk cumsum of A*dt
    acum_kernel<<<BATCH * NCHUNK * NHEADS, 64, 0, stream>>>(dtb, A_log, Acum);
    // 4) G = C @ B^T per (b,c)
    gchunk_kernel<<<BATCH * NCHUNK, 256, 0, stream>>>(xBC, Gbuf);
    // 5) per-chunk states (overwrites R/u_bf16 region — both dead now)
    states_kernel<<<BATCH * NCHUNK * NHEADS, 256, 0, stream>>>(xBC, dtb, Acum, states);
    // 6) inter-chunk scan (in place: states -> entering state)
    scan_kernel<<<(BATCH * NHEADS * HEADDIM * D_STATE) / 256, 256, 0, stream>>>(Acum, states);
    // 7) Y_diag + D*x -> y
    ydiag_kernel<<<BATCH * NCHUNK * NHEADS, 256, 0, stream>>>(xBC, dtb, Acum, Gbuf, Dv, y);
    // 8) Y_off += C @ prev_state * exp(ac)
    yoff_kernel<<<BATCH * NCHUNK * NHEADS, 256, 0, stream>>>(xBC, Acum, states, y);
    // 9) gate + RMSNorm (in place on y)
    gate_norm_kernel<<<ROWS, 256, 0, stream>>>(Z, norm_w, y);
    // 10) out = y @ W_out
    gemm_mfma_bt<float><<<dim3(D_MODEL / 128, ROWS / 128), 256, 0, stream>>>(
        y, D_INNER, W_outT, D_INNER, out, D_MODEL, ROWS, D_MODEL, D_INNER);
}

// Round 5
// 583.592 us; speedup vs baseline: 4.2978x; 1.3650x over previous
//
#include <hip/hip_runtime.h>
#include <hip/hip_bf16.h>
#include <math.h>

#define D_MODEL   1024
#define D_STATE   128
#define HEADDIM   64
#define CHUNK     64
#define D_INNER   2048
#define NHEADS    32
#define D_IN_PROJ 4384   // 2*2048 + 2*128 + 32
#define CONV_CH   2304   // 2048 + 256
#define RCOLS     2336   // CONV_CH + NHEADS (xBC-raw + dt-raw columns)
#define WINT_ROWS 4480   // D_IN_PROJ padded so R-GEMM's 19th tile stays in-bounds
#define BATCH     2
#define SEQ       4096
#define NCHUNK    64     // SEQ / CHUNK
#define ROWS      (BATCH*SEQ)   // 8192
#define EPS_RMS   1e-5f

typedef __hip_bfloat16 bf16;
typedef __bf16 bf16x8_t __attribute__((ext_vector_type(8)));
typedef float  f32x4_t  __attribute__((ext_vector_type(4)));

__device__ __forceinline__ float siluf_(float x){ return x/(1.f+expf(-x)); }
__device__ __forceinline__ float ldf(const float* p){ return *p; }
__device__ __forceinline__ float ldf(const bf16* p){ return __bfloat162float(*p); }
__device__ __forceinline__ void  stf(float* p, float v){ *p = v; }
__device__ __forceinline__ void  stf(bf16* p, float v){ *p = __float2bfloat16(v); }

__device__ __forceinline__ __bf16 tobf(float v){
    __hip_bfloat16 t = __float2bfloat16(v);
    return *reinterpret_cast<__bf16*>(&t);
}
__device__ __forceinline__ float bfbits2f(unsigned short u){
    union { unsigned u; float f; } cv; cv.u = ((unsigned)u) << 16; return cv.f;
}

// async global->LDS, 16 B per lane; LDS dest is wave-uniform base + lane*16.
__device__ __forceinline__ void async16(const void* g, void* l) {
    __builtin_amdgcn_global_load_lds(
        (const __attribute__((address_space(1))) unsigned int*)g,
        (__attribute__((address_space(3))) unsigned int*)l, 16, 0, 0);
}

// ---------------------------------------------------------------------------
// MFMA GEMM: C[M,N] = A[M,K] @ Bt[N,K]^T.  (verified round-4 kernel, unchanged)
// mfma convention used everywhere in this file:
//   a-frag = rows of the M-by-K matrix   (lane holds row m=lane&15, k=(lane>>4)*8+j)
//   b-frag = rows of the N-by-K matrix   (same per-lane layout)
//   D[m][n]: col n = lane&15, row m = (lane>>4)*4 + reg     [m89/m91]
// ---------------------------------------------------------------------------
template <typename TC>
__global__ __launch_bounds__(256) void gemm_mfma_bt(const bf16* __restrict__ A, int lda,
                                                    const bf16* __restrict__ Bt, int ldb,
                                                    TC* __restrict__ C, int ldc,
                                                    int M, int N, int K) {
    __shared__ __align__(16) __bf16 As[128 * 32];
    __shared__ __align__(16) __bf16 Bs[128 * 32];
    const int tid  = threadIdx.x;
    const int wave = tid >> 6, lane = tid & 63;
    const int quad = lane >> 4, l16 = lane & 15;
    const int row0 = blockIdx.y * 128, col0 = blockIdx.x * 128;
    const int wr = (wave >> 1) * 64;
    const int wc = (wave & 1) * 64;

    f32x4_t acc[4][4];
#pragma unroll
    for (int i = 0; i < 4; ++i)
#pragma unroll
        for (int j = 0; j < 4; ++j) acc[i][j] = (f32x4_t){0.f, 0.f, 0.f, 0.f};

    const int ca0 = wave * 2, ca1 = wave * 2 + 1;
    const int srow = lane >> 2, scol = (lane & 3) * 8;
    const bf16* Ag0 = A  + (size_t)(row0 + ca0 * 16 + srow) * lda + scol;
    const bf16* Ag1 = A  + (size_t)(row0 + ca1 * 16 + srow) * lda + scol;
    const bf16* Bg0 = Bt + (size_t)(col0 + ca0 * 16 + srow) * ldb + scol;
    const bf16* Bg1 = Bt + (size_t)(col0 + ca1 * 16 + srow) * ldb + scol;
    __bf16* Al0 = As + ca0 * 512;
    __bf16* Al1 = As + ca1 * 512;
    __bf16* Bl0 = Bs + ca0 * 512;
    __bf16* Bl1 = Bs + ca1 * 512;

    for (int kk = 0; kk < K; kk += 32) {
        async16(Ag0 + kk, Al0);
        async16(Ag1 + kk, Al1);
        async16(Bg0 + kk, Bl0);
        async16(Bg1 + kk, Bl1);
        __syncthreads();
        bf16x8_t af[4], bfr[4];
#pragma unroll
        for (int mi = 0; mi < 4; ++mi)
            af[mi] = *(const bf16x8_t*)(As + (wr + mi * 16 + l16) * 32 + quad * 8);
#pragma unroll
        for (int ni = 0; ni < 4; ++ni)
            bfr[ni] = *(const bf16x8_t*)(Bs + (wc + ni * 16 + l16) * 32 + quad * 8);
#pragma unroll
        for (int mi = 0; mi < 4; ++mi)
#pragma unroll
            for (int ni = 0; ni < 4; ++ni)
                acc[mi][ni] = __builtin_amdgcn_mfma_f32_16x16x32_bf16(
                    af[mi], bfr[ni], acc[mi][ni], 0, 0, 0);
        __syncthreads();
    }

#pragma unroll
    for (int ni = 0; ni < 4; ++ni) {
        int gc = col0 + wc + ni * 16 + l16;
        if (gc >= N) continue;
#pragma unroll
        for (int mi = 0; mi < 4; ++mi) {
#pragma unroll
            for (int r = 0; r < 4; ++r) {
                int gr = row0 + wr + mi * 16 + quad * 4 + r;
                stf(&C[(size_t)gr * ldc + gc], acc[mi][ni][r]);
            }
        }
    }
}

// fp32 -> bf16 cast, 4 elems/thread
__global__ void cvt_bf16_kernel(const float* __restrict__ src,
                                bf16* __restrict__ dst, int n4) {
    int i = blockIdx.x * 256 + threadIdx.x;
    if (i >= n4) return;
    float4 v = ((const float4*)src)[i];
    dst[i * 4 + 0] = __float2bfloat16(v.x);
    dst[i * 4 + 1] = __float2bfloat16(v.y);
    dst[i * 4 + 2] = __float2bfloat16(v.z);
    dst[i * 4 + 3] = __float2bfloat16(v.w);
}

// Wt[c][r] = W[r][c], fp32 -> bf16.
__global__ __launch_bounds__(256) void transpose_cvt_kernel(const float* __restrict__ W,
                                                            bf16* __restrict__ Wt,
                                                            int R, int C, int Cpad) {
    __shared__ float tile[32][33];
    int c0 = blockIdx.x * 32, r0 = blockIdx.y * 32;
    int tx = threadIdx.x & 31, ty = threadIdx.x >> 5;
    for (int i = ty; i < 32; i += 8) {
        int r = r0 + i, c = c0 + tx;
        tile[i][tx] = (c < C) ? W[(size_t)r * C + c] : 0.f;
    }
    __syncthreads();
    for (int i = ty; i < 32; i += 8) {
        int c = c0 + i, r = r0 + tx;
        stf(&Wt[(size_t)c * R + r], tile[tx][i]);
    }
}

// ---------------------------------------------------------------------------
// Depthwise causal conv (k=4) + bias + SiLU.
// ---------------------------------------------------------------------------
__global__ void conv_silu_kernel(const bf16* __restrict__ R,
                                 const float* __restrict__ conv_w,
                                 const float* __restrict__ conv_b,
                                 bf16* __restrict__ xBC) {
    int ch = blockIdx.x * 256 + threadIdx.x;
    int row = blockIdx.y;
    if (ch >= CONV_CH) return;
    int l = row & (SEQ - 1);
    int b = row >> 12;
    float acc = conv_b[ch];
#pragma unroll
    for (int k = 0; k < 4; ++k) {
        int ls = l - 3 + k;
        if (ls >= 0)
            acc += conv_w[ch * 4 + k] *
                   ldf(&R[(size_t)(b * SEQ + ls) * RCOLS + ch]);
    }
    stf(&xBC[(size_t)row * CONV_CH + ch], siluf_(acc));
}

// dt[row][h] = softplus(R[row][CONV_CH+h] + dt_bias[h])
__global__ void dt_kernel(const bf16* __restrict__ R,
                          const float* __restrict__ dt_bias,
                          float* __restrict__ dtb) {
    int i = blockIdx.x * 256 + threadIdx.x;
    if (i >= ROWS * NHEADS) return;
    int row = i >> 5, h = i & 31;
    float v = ldf(&R[(size_t)row * RCOLS + CONV_CH + h]) + dt_bias[h];
    dtb[i] = (v > 20.f) ? v : log1pf(expf(v));
}

// Per (b,c,h): inclusive cumsum of A[h]*dt over the 64-long chunk.
__global__ void acum_kernel(const float* __restrict__ dtb,
                            const float* __restrict__ A_log,
                            float* __restrict__ Acum) {
    int bch = blockIdx.x;
    int h = bch & 31;
    int bc = bch >> 5;
    int c = bc & 63, b = bc >> 6;
    int row0 = b * SEQ + c * CHUNK;
    __shared__ float sh[64];
    int l = threadIdx.x;
    float Ah = -expf(A_log[h]);
    sh[l] = Ah * dtb[(size_t)(row0 + l) * NHEADS + h];
    __syncthreads();
    float s = 0.f;
    for (int j = 0; j <= l; ++j) s += sh[j];
    Acum[(size_t)bch * 64 + l] = s;
}

// Per (b,c): G[l][s] = sum_n C[l,n]*B[s,n]   (head independent, fp32 out)
__global__ __launch_bounds__(256) void gchunk_kernel(const bf16* __restrict__ xBC,
                                                     float* __restrict__ Gbuf) {
    int bc = blockIdx.x;
    int c = bc & 63, b = bc >> 6;
    int row0 = b * SEQ + c * CHUNK;
    __shared__ float Bs[64 * 129];
    int tid = threadIdx.x;
    for (int i = tid; i < 64 * 128; i += 256) {
        int l = i >> 7, n = i & 127;
        Bs[l * 129 + n] = ldf(&xBC[(size_t)(row0 + l) * CONV_CH + D_INNER + n]);
    }
    __syncthreads();
    for (int i = tid; i < 64 * 64; i += 256) {
        int l = i >> 6, s = i & 63;
        const bf16* Crow = xBC + (size_t)(row0 + l) * CONV_CH + D_INNER + D_STATE;
        float acc = 0.f;
#pragma unroll 8
        for (int n = 0; n < 128; ++n) acc += ldf(&Crow[n]) * Bs[s * 129 + n];
        Gbuf[(size_t)bc * 4096 + i] = acc;
    }
}

// ---------------------------------------------------------------------------
// MFMA chunk-states: S[p][n] = sum_l (x[l,p]*dt[l]*dec[l]) * B[l,n].
// Block = 4 waves = 4 heads of one (b,c); BsT (B transposed) shared.
// a-frag rows from xdT[p][l] (M=64 p, K=64 l); b-frag rows from BsT[n][l].
// ---------------------------------------------------------------------------
__global__ __launch_bounds__(256) void states_mfma_kernel(const bf16* __restrict__ xBC,
                                                          const float* __restrict__ dtb,
                                                          const float* __restrict__ Acum,
                                                          bf16* __restrict__ states) {
    __shared__ __align__(16) __bf16 BsT[128 * 72];      // [n][l], stride 72 (144 B)
    __shared__ __align__(16) __bf16 xdT[4][64 * 72];    // per-wave [p][l]
    __shared__ float dtdec[4][64];
    int bcq = blockIdx.x;                 // (b*64+c)*8 + hq
    int hq = bcq & 7, bc = bcq >> 3;
    int c = bc & 63, b = bc >> 6;
    int tid = threadIdx.x, wave = tid >> 6, lane = tid & 63;
    int h = hq * 4 + wave;
    int bch = bc * 32 + h;
    int row0 = b * SEQ + c * CHUNK;
    int quad = lane >> 4, l16 = lane & 15;

    {   // dt[l] * exp(Ac63 - Ac[l]) per head, lane = l
        float alast = Acum[(size_t)bch * 64 + 63];
        float a = Acum[(size_t)bch * 64 + lane];
        dtdec[wave][lane] = dtb[(size_t)(row0 + lane) * NHEADS + h] * expf(alast - a);
    }
    __syncthreads();
    // BsT staging (cooperative): read B[l][n0..n0+1] coalesced, write transposed
    for (int it = 0; it < 16; ++it) {
        int i2 = tid + 256 * it;          // 0..4095
        int l = i2 >> 6;
        int n0 = (i2 & 63) * 2;
        unsigned v = *(const unsigned*)&xBC[(size_t)(row0 + l) * CONV_CH + D_INNER + n0];
        *(unsigned short*)&BsT[(n0    ) * 72 + l] = (unsigned short)(v & 0xffff);
        *(unsigned short*)&BsT[(n0 + 1) * 72 + l] = (unsigned short)(v >> 16);
    }
    // xdT staging (per wave): x[l][p0..p0+1] * dtdec[l], write transposed
    for (int it = 0; it < 32; ++it) {
        int l = 2 * it + (lane >> 5);
        int p0 = (lane & 31) * 2;
        unsigned v = *(const unsigned*)&xBC[(size_t)(row0 + l) * CONV_CH + h * 64 + p0];
        float f = dtdec[wave][l];
        xdT[wave][(p0    ) * 72 + l] = tobf(bfbits2f((unsigned short)(v & 0xffff)) * f);
        xdT[wave][(p0 + 1) * 72 + l] = tobf(bfbits2f((unsigned short)(v >> 16)) * f);
    }
    __syncthreads();

    f32x4_t acc[4][8];
#pragma unroll
    for (int i = 0; i < 4; ++i)
#pragma unroll
        for (int j = 0; j < 8; ++j) acc[i][j] = (f32x4_t){0.f, 0.f, 0.f, 0.f};
#pragma unroll
    for (int ks = 0; ks < 2; ++ks) {
        bf16x8_t a[4], bb[8];
#pragma unroll
        for (int mi = 0; mi < 4; ++mi)
            a[mi] = *(const bf16x8_t*)(&xdT[wave][(mi * 16 + l16) * 72 + ks * 32 + quad * 8]);
#pragma unroll
        for (int ni = 0; ni < 8; ++ni)
            bb[ni] = *(const bf16x8_t*)(&BsT[(ni * 16 + l16) * 72 + ks * 32 + quad * 8]);
#pragma unroll
        for (int mi = 0; mi < 4; ++mi)
#pragma unroll
            for (int ni = 0; ni < 8; ++ni)
                acc[mi][ni] = __builtin_amdgcn_mfma_f32_16x16x32_bf16(
                    a[mi], bb[ni], acc[mi][ni], 0, 0, 0);
    }
    // store: col = n (lane&15), rows = p = quad*4+r
#pragma unroll
    for (int ni = 0; ni < 8; ++ni) {
        int n = ni * 16 + l16;
#pragma unroll
        for (int mi = 0; mi < 4; ++mi)
#pragma unroll
            for (int r = 0; r < 4; ++r) {
                int p = mi * 16 + quad * 4 + r;
                stf(&states[(size_t)bch * 8192 + p * 128 + n], acc[mi][ni][r]);
            }
    }
}

// Inter-chunk scan (in place): states[b,c,h,p,n] -> state ENTERING chunk c.
__global__ void scan_kernel(const float* __restrict__ Acum,
                            bf16* __restrict__ states) {
    int i = blockIdx.x * 256 + threadIdx.x;
    int pn = i & 8191;
    int bh = i >> 13;
    int h = bh & 31, b = bh >> 5;
    float carry = 0.f;
    for (int c = 0; c < NCHUNK; ++c) {
        int bch = (b * NCHUNK + c) * NHEADS + h;
        size_t idx = (size_t)bch * 8192 + pn;
        float s = ldf(&states[idx]);
        stf(&states[idx], carry);
        carry = carry * expf(Acum[(size_t)bch * 64 + 63]) + s;
    }
}

// ---------------------------------------------------------------------------
// MFMA Y: Y[l][p] = sum_s M[l][s]*x[s][p]  +  sum_n (C[l][n]*sdo[l])*state[p][n]
//                  + D[h]*x[l][p]
// with M[l][s] = tril(G[l][s]*exp(ac[l]-ac[s])*dt[s]).  One wave per (b,c,h).
// part1: a-frag rows of Mm (K=s), b-frag rows of xsT[p][s].
// part2: a-frag rows of C*sdo from global (K=n), b-frag rows of states[p][n].
// ---------------------------------------------------------------------------
__global__ __launch_bounds__(64) void y_mfma_kernel(const bf16* __restrict__ xBC,
                                                    const float* __restrict__ dtb,
                                                    const float* __restrict__ Acum,
                                                    const float* __restrict__ Gbuf,
                                                    const bf16* __restrict__ states,
                                                    const float* __restrict__ Dv,
                                                    bf16* __restrict__ y) {
    __shared__ __align__(16) __bf16 Mm[64 * 72];    // [l][s]
    __shared__ __align__(16) __bf16 xsT[64 * 72];   // [p][s] (plain x, transposed)
    __shared__ float acs[64], dtss[64], sdos[64];
    int bch = blockIdx.x;
    int h = bch & 31, bc = bch >> 5;
    int c = bc & 63, b = bc >> 6;
    int row0 = b * SEQ + c * CHUNK;
    int lane = threadIdx.x;
    int quad = lane >> 4, l16 = lane & 15;

    {   // per-l scalars (lane = l)
        float a = Acum[(size_t)bch * 64 + lane];
        acs[lane] = a;
        sdos[lane] = expf(a);
        dtss[lane] = dtb[(size_t)(row0 + lane) * NHEADS + h];
    }
    __syncthreads();
    // Mm[l][s]
    for (int l = 0; l < 64; ++l) {
        int s = lane;
        float d = acs[l] - acs[s];
        float g = (s <= l) ? Gbuf[(size_t)bc * 4096 + l * 64 + s] * dtss[s] : 0.f;
        float coef = g * expf((s <= l) ? d : 0.f);
        Mm[l * 72 + s] = tobf(coef);
    }
    // xsT[p][l] = x[l][p]
    for (int it = 0; it < 32; ++it) {
        int l = 2 * it + (lane >> 5);
        int p0 = (lane & 31) * 2;
        unsigned v = *(const unsigned*)&xBC[(size_t)(row0 + l) * CONV_CH + h * 64 + p0];
        *(unsigned short*)&xsT[(p0    ) * 72 + l] = (unsigned short)(v & 0xffff);
        *(unsigned short*)&xsT[(p0 + 1) * 72 + l] = (unsigned short)(v >> 16);
    }
    __syncthreads();

    f32x4_t acc[4][4];
#pragma unroll
    for (int i = 0; i < 4; ++i)
#pragma unroll
        for (int j = 0; j < 4; ++j) acc[i][j] = (f32x4_t){0.f, 0.f, 0.f, 0.f};

    // part 1: Y += M @ x   (K = 64 over s)
#pragma unroll
    for (int ks = 0; ks < 2; ++ks) {
        bf16x8_t a[4], bb[4];
#pragma unroll
        for (int mi = 0; mi < 4; ++mi)
            a[mi] = *(const bf16x8_t*)(&Mm[(mi * 16 + l16) * 72 + ks * 32 + quad * 8]);
#pragma unroll
        for (int ni = 0; ni < 4; ++ni)
            bb[ni] = *(const bf16x8_t*)(&xsT[(ni * 16 + l16) * 72 + ks * 32 + quad * 8]);
#pragma unroll
        for (int mi = 0; mi < 4; ++mi)
#pragma unroll
            for (int ni = 0; ni < 4; ++ni)
                acc[mi][ni] = __builtin_amdgcn_mfma_f32_16x16x32_bf16(
                    a[mi], bb[ni], acc[mi][ni], 0, 0, 0);
    }
    // part 2: Y += (C*sdo) @ state^T   (K = 128 over n)
    float sdo_mi[4];
#pragma unroll
    for (int mi = 0; mi < 4; ++mi) sdo_mi[mi] = sdos[mi * 16 + l16];
#pragma unroll
    for (int ks = 0; ks < 4; ++ks) {
        bf16x8_t a[4], bb[4];
#pragma unroll
        for (int mi = 0; mi < 4; ++mi) {
            const unsigned* cp = (const unsigned*)&xBC[(size_t)(row0 + mi * 16 + l16) * CONV_CH
                                                       + D_INNER + D_STATE + ks * 32 + quad * 8];
            float sc = sdo_mi[mi];
#pragma unroll
            for (int jj = 0; jj < 4; ++jj) {
                unsigned v = cp[jj];
                a[mi][2 * jj    ] = tobf(bfbits2f((unsigned short)(v & 0xffff)) * sc);
                a[mi][2 * jj + 1] = tobf(bfbits2f((unsigned short)(v >> 16)) * sc);
            }
        }
#pragma unroll
        for (int ni = 0; ni < 4; ++ni)
            bb[ni] = *(const bf16x8_t*)&states[(size_t)bch * 8192 + (ni * 16 + l16) * 128
                                               + ks * 32 + quad * 8];
#pragma unroll
        for (int mi = 0; mi < 4; ++mi)
#pragma unroll
            for (int ni = 0; ni < 4; ++ni)
                acc[mi][ni] = __builtin_amdgcn_mfma_f32_16x16x32_bf16(
                    a[mi], bb[ni], acc[mi][ni], 0, 0, 0);
    }
    // epilogue: + D*x, write y.  col = p (lane&15), rows l = quad*4+r
    float Dh = Dv[h];
#pragma unroll
    for (int ni = 0; ni < 4; ++ni) {
        int p = ni * 16 + l16;
#pragma unroll
        for (int mi = 0; mi < 4; ++mi)
#pragma unroll
            for (int r = 0; r < 4; ++r) {
                int l = mi * 16 + quad * 4 + r;
                float xv = bfbits2f(*(const unsigned short*)&xsT[p * 72 + l]);
                stf(&y[(size_t)(row0 + l) * D_INNER + h * 64 + p],
                    acc[mi][ni][r] + Dh * xv);
            }
    }
}

// Per row: v = y * silu(z); y = v * rsqrt(mean(v^2)+eps) * norm_w
__global__ __launch_bounds__(256) void gate_norm_kernel(const bf16* __restrict__ Z,
                                                        const float* __restrict__ nw,
                                                        bf16* __restrict__ y) {
    int row = blockIdx.x;
    int tid = threadIdx.x;
    float vals[8];
    float local = 0.f;
#pragma unroll
    for (int i = 0; i < 8; ++i) {
        int col = tid + i * 256;
        float z = ldf(&Z[(size_t)row * D_INNER + col]);
        float v = ldf(&y[(size_t)row * D_INNER + col]) * siluf_(z);
        vals[i] = v;
        local += v * v;
    }
#pragma unroll
    for (int off = 32; off; off >>= 1) local += __shfl_down(local, off, 64);
    __shared__ float wsum[4];
    if ((tid & 63) == 0) wsum[tid >> 6] = local;
    __syncthreads();
    float total = wsum[0] + wsum[1] + wsum[2] + wsum[3];
    float scale = rsqrtf(total / (float)D_INNER + EPS_RMS);
#pragma unroll
    for (int i = 0; i < 8; ++i) {
        int col = tid + i * 256;
        stf(&y[(size_t)row * D_INNER + col], vals[i] * scale * nw[col]);
    }
}

// ---------------------------------------------------------------------------
extern "C" void kernel_launch(void* const* d_in, const int* in_sizes, int n_in,
                              void* d_out, int out_size, void* d_ws, size_t ws_size,
                              hipStream_t stream) {
    const float* u       = (const float*)d_in[0];
    const float* W_in    = (const float*)d_in[1];
    const float* conv_w  = (const float*)d_in[2];
    const float* conv_b  = (const float*)d_in[3];
    const float* dt_bias = (const float*)d_in[4];
    const float* A_log   = (const float*)d_in[5];
    const float* Dv      = (const float*)d_in[6];
    const float* norm_w  = (const float*)d_in[7];
    const float* W_out   = (const float*)d_in[8];
    float* out = (float*)d_out;

    const size_t sz_xBC    = (size_t)ROWS * CONV_CH * 2;
    const size_t sz_Z      = (size_t)ROWS * D_INNER * 2;
    const size_t sz_y      = (size_t)ROWS * D_INNER * 2;
    const size_t sz_states = (size_t)BATCH * NCHUNK * NHEADS * 8192 * 2;
    const size_t sz_dtb    = (size_t)ROWS * NHEADS * 4;
    const size_t sz_Acum   = (size_t)BATCH * NCHUNK * NHEADS * 64 * 4;
    const size_t sz_Gbuf   = (size_t)BATCH * NCHUNK * 4096 * 4;
    const size_t sz_WinT   = (size_t)WINT_ROWS * D_MODEL * 2;
    const size_t sz_WoutT  = (size_t)D_MODEL * D_INNER * 2;
    const size_t need = sz_xBC + sz_Z + sz_y + sz_states + sz_dtb + sz_Acum +
                        sz_Gbuf + sz_WinT + sz_WoutT;
    if (ws_size < need) {
        hipMemsetAsync(d_out, 0, (size_t)out_size * sizeof(float), stream);
        return;
    }
    char* ws = (char*)d_ws;
    size_t off = 0;
    bf16*  xBC    = (bf16*) (ws + off); off += sz_xBC;
    bf16*  Z      = (bf16*) (ws + off); off += sz_Z;
    bf16*  y      = (bf16*) (ws + off); off += sz_y;
    bf16*  states = (bf16*) (ws + off); off += sz_states;
    float* dtb    = (float*)(ws + off); off += sz_dtb;
    float* Acum   = (float*)(ws + off); off += sz_Acum;
    float* Gbuf   = (float*)(ws + off); off += sz_Gbuf;
    bf16*  W_inT  = (bf16*) (ws + off); off += sz_WinT;
    bf16*  W_outT = (bf16*) (ws + off); off += sz_WoutT;
    // R (38.3 MB) and u_bf16 (16.8 MB) alias states (67.1 MB); both dead
    // before states_mfma_kernel writes it.
    bf16* R      = states;
    bf16* u_bf16 = (bf16*)((char*)states + (size_t)ROWS * RCOLS * 2);

    // 0) prep
    cvt_bf16_kernel<<<(ROWS * D_MODEL / 4 + 255) / 256, 256, 0, stream>>>(
        u, u_bf16, ROWS * D_MODEL / 4);
    transpose_cvt_kernel<<<dim3(WINT_ROWS / 32, D_MODEL / 32), 256, 0, stream>>>(
        W_in, W_inT, D_MODEL, D_IN_PROJ, WINT_ROWS);
    transpose_cvt_kernel<<<dim3(D_MODEL / 32, D_INNER / 32), 256, 0, stream>>>(
        W_out, W_outT, D_INNER, D_MODEL, D_MODEL);
    // 1) GEMM1 split
    gemm_mfma_bt<bf16><<<dim3(D_INNER / 128, ROWS / 128), 256, 0, stream>>>(
        u_bf16, D_MODEL, W_inT, D_MODEL, Z, D_INNER, ROWS, D_INNER, D_MODEL);
    gemm_mfma_bt<bf16><<<dim3((RCOLS + 127) / 128, ROWS / 128), 256, 0, stream>>>(
        u_bf16, D_MODEL, W_inT + (size_t)D_INNER * D_MODEL, D_MODEL,
        R, RCOLS, ROWS, RCOLS, D_MODEL);
    // 2) conv + silu ; dt
    conv_silu_kernel<<<dim3(9, ROWS), 256, 0, stream>>>(R, conv_w, conv_b, xBC);
    dt_kernel<<<(ROWS * NHEADS) / 256, 256, 0, stream>>>(R, dt_bias, dtb);
    // 3) per-chunk cumsum of A*dt
    acum_kernel<<<BATCH * NCHUNK * NHEADS, 64, 0, stream>>>(dtb, A_log, Acum);
    // 4) G = C @ B^T per (b,c)
    gchunk_kernel<<<BATCH * NCHUNK, 256, 0, stream>>>(xBC, Gbuf);
    // 5) per-chunk states (MFMA; overwrites R/u_bf16 aliases — both dead)
    states_mfma_kernel<<<BATCH * NCHUNK * 8, 256, 0, stream>>>(xBC, dtb, Acum, states);
    // 6) inter-chunk scan
    scan_kernel<<<(BATCH * NHEADS * HEADDIM * D_STATE) / 256, 256, 0, stream>>>(Acum, states);
    // 7+8) Y = diag + off + D*x  (MFMA, fused)
    y_mfma_kernel<<<BATCH * NCHUNK * NHEADS, 64, 0, stream>>>(
        xBC, dtb, Acum, Gbuf, states, Dv, y);
    // 9) gate + RMSNorm
    gate_norm_kernel<<<ROWS, 256, 0, stream>>>(Z, norm_w, y);
    // 10) out = y @ W_out
    gemm_mfma_bt<float><<<dim3(D_MODEL / 128, ROWS / 128), 256, 0, stream>>>(
        y, D_INNER, W_outT, D_INNER, out, D_MODEL, ROWS, D_MODEL, D_INNER);
}

// Round 6
// 518.925 us; speedup vs baseline: 4.8334x; 1.1246x over previous
//
#include <hip/hip_runtime.h>
#include <hip/hip_bf16.h>
#include <math.h>

#define D_MODEL   1024
#define D_STATE   128
#define HEADDIM   64
#define CHUNK     64
#define D_INNER   2048
#define NHEADS    32
#define D_IN_PROJ 4384   // 2*2048 + 2*128 + 32
#define CONV_CH   2304   // 2048 + 256
#define RCOLS     2336   // CONV_CH + NHEADS (xBC-raw + dt-raw columns)
#define WINT_ROWS 4480   // D_IN_PROJ padded so R-GEMM's 19th tile stays in-bounds
#define BATCH     2
#define SEQ       4096
#define NCHUNK    64     // SEQ / CHUNK
#define ROWS      (BATCH*SEQ)   // 8192
#define EPS_RMS   1e-5f

typedef __hip_bfloat16 bf16;
typedef __bf16 bf16x8_t __attribute__((ext_vector_type(8)));
typedef float  f32x4_t  __attribute__((ext_vector_type(4)));

__device__ __forceinline__ float siluf_(float x){ return x/(1.f+expf(-x)); }
__device__ __forceinline__ float ldf(const float* p){ return *p; }
__device__ __forceinline__ float ldf(const bf16* p){ return __bfloat162float(*p); }
__device__ __forceinline__ void  stf(float* p, float v){ *p = v; }
__device__ __forceinline__ void  stf(bf16* p, float v){ *p = __float2bfloat16(v); }

__device__ __forceinline__ __bf16 tobf(float v){
    __hip_bfloat16 t = __float2bfloat16(v);
    return *reinterpret_cast<__bf16*>(&t);
}
__device__ __forceinline__ unsigned short bfbits(float v){
    __hip_bfloat16 t = __float2bfloat16(v);
    return *reinterpret_cast<unsigned short*>(&t);
}
__device__ __forceinline__ float bfbits2f(unsigned short u){
    union { unsigned u; float f; } cv; cv.u = ((unsigned)u) << 16; return cv.f;
}

// async global->LDS, 16 B per lane; LDS dest is wave-uniform base + lane*16.
__device__ __forceinline__ void async16(const void* g, void* l) {
    __builtin_amdgcn_global_load_lds(
        (const __attribute__((address_space(1))) unsigned int*)g,
        (__attribute__((address_space(3))) unsigned int*)l, 16, 0, 0);
}

// ---------------------------------------------------------------------------
// MFMA GEMM: C[M,N] = A[M,K] @ Bt[N,K]^T.  (verified round-4 kernel, unchanged)
// mfma convention used everywhere in this file:
//   a-frag = rows of the M-by-K matrix   (lane holds row m=lane&15, k=(lane>>4)*8+j)
//   b-frag = rows of the N-by-K matrix   (same per-lane layout)
//   D[m][n]: col n = lane&15, row m = (lane>>4)*4 + reg     [m89/m91]
// ---------------------------------------------------------------------------
template <typename TC>
__global__ __launch_bounds__(256) void gemm_mfma_bt(const bf16* __restrict__ A, int lda,
                                                    const bf16* __restrict__ Bt, int ldb,
                                                    TC* __restrict__ C, int ldc,
                                                    int M, int N, int K) {
    __shared__ __align__(16) __bf16 As[128 * 32];
    __shared__ __align__(16) __bf16 Bs[128 * 32];
    const int tid  = threadIdx.x;
    const int wave = tid >> 6, lane = tid & 63;
    const int quad = lane >> 4, l16 = lane & 15;
    const int row0 = blockIdx.y * 128, col0 = blockIdx.x * 128;
    const int wr = (wave >> 1) * 64;
    const int wc = (wave & 1) * 64;

    f32x4_t acc[4][4];
#pragma unroll
    for (int i = 0; i < 4; ++i)
#pragma unroll
        for (int j = 0; j < 4; ++j) acc[i][j] = (f32x4_t){0.f, 0.f, 0.f, 0.f};

    const int ca0 = wave * 2, ca1 = wave * 2 + 1;
    const int srow = lane >> 2, scol = (lane & 3) * 8;
    const bf16* Ag0 = A  + (size_t)(row0 + ca0 * 16 + srow) * lda + scol;
    const bf16* Ag1 = A  + (size_t)(row0 + ca1 * 16 + srow) * lda + scol;
    const bf16* Bg0 = Bt + (size_t)(col0 + ca0 * 16 + srow) * ldb + scol;
    const bf16* Bg1 = Bt + (size_t)(col0 + ca1 * 16 + srow) * ldb + scol;
    __bf16* Al0 = As + ca0 * 512;
    __bf16* Al1 = As + ca1 * 512;
    __bf16* Bl0 = Bs + ca0 * 512;
    __bf16* Bl1 = Bs + ca1 * 512;

    for (int kk = 0; kk < K; kk += 32) {
        async16(Ag0 + kk, Al0);
        async16(Ag1 + kk, Al1);
        async16(Bg0 + kk, Bl0);
        async16(Bg1 + kk, Bl1);
        __syncthreads();
        bf16x8_t af[4], bfr[4];
#pragma unroll
        for (int mi = 0; mi < 4; ++mi)
            af[mi] = *(const bf16x8_t*)(As + (wr + mi * 16 + l16) * 32 + quad * 8);
#pragma unroll
        for (int ni = 0; ni < 4; ++ni)
            bfr[ni] = *(const bf16x8_t*)(Bs + (wc + ni * 16 + l16) * 32 + quad * 8);
#pragma unroll
        for (int mi = 0; mi < 4; ++mi)
#pragma unroll
            for (int ni = 0; ni < 4; ++ni)
                acc[mi][ni] = __builtin_amdgcn_mfma_f32_16x16x32_bf16(
                    af[mi], bfr[ni], acc[mi][ni], 0, 0, 0);
        __syncthreads();
    }

#pragma unroll
    for (int ni = 0; ni < 4; ++ni) {
        int gc = col0 + wc + ni * 16 + l16;
        if (gc >= N) continue;
#pragma unroll
        for (int mi = 0; mi < 4; ++mi) {
#pragma unroll
            for (int r = 0; r < 4; ++r) {
                int gr = row0 + wr + mi * 16 + quad * 4 + r;
                stf(&C[(size_t)gr * ldc + gc], acc[mi][ni][r]);
            }
        }
    }
}

// fp32 -> bf16 cast, 4 elems/thread
__global__ void cvt_bf16_kernel(const float* __restrict__ src,
                                bf16* __restrict__ dst, int n4) {
    int i = blockIdx.x * 256 + threadIdx.x;
    if (i >= n4) return;
    float4 v = ((const float4*)src)[i];
    dst[i * 4 + 0] = __float2bfloat16(v.x);
    dst[i * 4 + 1] = __float2bfloat16(v.y);
    dst[i * 4 + 2] = __float2bfloat16(v.z);
    dst[i * 4 + 3] = __float2bfloat16(v.w);
}

// Wt[c][r] = W[r][c], fp32 -> bf16.
__global__ __launch_bounds__(256) void transpose_cvt_kernel(const float* __restrict__ W,
                                                            bf16* __restrict__ Wt,
                                                            int R, int C, int Cpad) {
    __shared__ float tile[32][33];
    int c0 = blockIdx.x * 32, r0 = blockIdx.y * 32;
    int tx = threadIdx.x & 31, ty = threadIdx.x >> 5;
    for (int i = ty; i < 32; i += 8) {
        int r = r0 + i, c = c0 + tx;
        tile[i][tx] = (c < C) ? W[(size_t)r * C + c] : 0.f;
    }
    __syncthreads();
    for (int i = ty; i < 32; i += 8) {
        int c = c0 + i, r = r0 + tx;
        stf(&Wt[(size_t)c * R + r], tile[tx][i]);
    }
}

// ---------------------------------------------------------------------------
// Depthwise causal conv (k=4) + bias + SiLU, vectorized: one thread = one row
// x 8 channels.  16 B loads of R, float4 weight loads, 16 B store.
// ---------------------------------------------------------------------------
__global__ __launch_bounds__(256) void conv_silu_kernel(const bf16* __restrict__ R,
                                                        const float* __restrict__ conv_w,
                                                        const float* __restrict__ conv_b,
                                                        bf16* __restrict__ xBC) {
    int idx = blockIdx.x * 256 + threadIdx.x;       // ROWS * 288 exactly
    int row = idx / 288;
    int g = idx - row * 288;
    int ch0 = g * 8;
    int l = row & (SEQ - 1);
    int b = row >> 12;

    float acc[8];
    {
        float4 b0 = ((const float4*)conv_b)[ch0 / 4];
        float4 b1 = ((const float4*)conv_b)[ch0 / 4 + 1];
        acc[0] = b0.x; acc[1] = b0.y; acc[2] = b0.z; acc[3] = b0.w;
        acc[4] = b1.x; acc[5] = b1.y; acc[6] = b1.z; acc[7] = b1.w;
    }
    float4 w4[8];
#pragma unroll
    for (int j = 0; j < 8; ++j) w4[j] = ((const float4*)conv_w)[ch0 + j];

#pragma unroll
    for (int k = 0; k < 4; ++k) {
        int ls = l - 3 + k;
        if (ls < 0) continue;
        uint4 v = *(const uint4*)&R[(size_t)(b * SEQ + ls) * RCOLS + ch0];
        const unsigned vv[4] = {v.x, v.y, v.z, v.w};
#pragma unroll
        for (int j = 0; j < 4; ++j) {
            float lo = bfbits2f((unsigned short)(vv[j] & 0xffff));
            float hi = bfbits2f((unsigned short)(vv[j] >> 16));
            float wk0 = (k == 0) ? w4[2*j].x : (k == 1) ? w4[2*j].y : (k == 2) ? w4[2*j].z : w4[2*j].w;
            float wk1 = (k == 0) ? w4[2*j+1].x : (k == 1) ? w4[2*j+1].y : (k == 2) ? w4[2*j+1].z : w4[2*j+1].w;
            acc[2*j]   += wk0 * lo;
            acc[2*j+1] += wk1 * hi;
        }
    }
    unsigned o[4];
#pragma unroll
    for (int j = 0; j < 4; ++j)
        o[j] = (unsigned)bfbits(siluf_(acc[2*j])) |
               ((unsigned)bfbits(siluf_(acc[2*j+1])) << 16);
    *(uint4*)&xBC[(size_t)row * CONV_CH + ch0] = make_uint4(o[0], o[1], o[2], o[3]);
}

// dt[row][h0..h0+7] = softplus(R[row][CONV_CH+h] + dt_bias[h]), vectorized.
__global__ void dt_kernel(const bf16* __restrict__ R,
                          const float* __restrict__ dt_bias,
                          float* __restrict__ dtb) {
    int i = blockIdx.x * 256 + threadIdx.x;         // ROWS*4 exactly
    int row = i >> 2, h0 = (i & 3) * 8;
    uint4 v = *(const uint4*)&R[(size_t)row * RCOLS + CONV_CH + h0];
    float4 bia0 = ((const float4*)dt_bias)[h0 / 4];
    float4 bia1 = ((const float4*)dt_bias)[h0 / 4 + 1];
    const unsigned vv[4] = {v.x, v.y, v.z, v.w};
    const float bb[8] = {bia0.x, bia0.y, bia0.z, bia0.w, bia1.x, bia1.y, bia1.z, bia1.w};
    float o[8];
#pragma unroll
    for (int j = 0; j < 4; ++j) {
        float a = bfbits2f((unsigned short)(vv[j] & 0xffff)) + bb[2*j];
        float c = bfbits2f((unsigned short)(vv[j] >> 16)) + bb[2*j+1];
        o[2*j]   = (a > 20.f) ? a : log1pf(expf(a));
        o[2*j+1] = (c > 20.f) ? c : log1pf(expf(c));
    }
    float* dp = &dtb[(size_t)row * NHEADS + h0];
    *(float4*)dp       = make_float4(o[0], o[1], o[2], o[3]);
    *(float4*)(dp + 4) = make_float4(o[4], o[5], o[6], o[7]);
}

// Per (b,c,h): inclusive cumsum of A[h]*dt over the 64-long chunk.
__global__ void acum_kernel(const float* __restrict__ dtb,
                            const float* __restrict__ A_log,
                            float* __restrict__ Acum) {
    int bch = blockIdx.x;
    int h = bch & 31;
    int bc = bch >> 5;
    int c = bc & 63, b = bc >> 6;
    int row0 = b * SEQ + c * CHUNK;
    __shared__ float sh[64];
    int l = threadIdx.x;
    float Ah = -expf(A_log[h]);
    sh[l] = Ah * dtb[(size_t)(row0 + l) * NHEADS + h];
    __syncthreads();
    float s = 0.f;
    for (int j = 0; j <= l; ++j) s += sh[j];
    Acum[(size_t)bch * 64 + l] = s;
}

// ---------------------------------------------------------------------------
// MFMA G-chunk: G[l][s] = sum_n C[l,n]*B[s,n].  One wave per (b,c).
// a-frag rows of C (M=64 l, K=128 n), b-frag rows of B (N=64 s, K=128 n),
// both straight from global (K-contiguous, 16 B aligned).  fp32 out.
// ---------------------------------------------------------------------------
__global__ __launch_bounds__(64) void gchunk_mfma_kernel(const bf16* __restrict__ xBC,
                                                         float* __restrict__ Gbuf) {
    int bc = blockIdx.x;
    int c = bc & 63, b = bc >> 6;
    int row0 = b * SEQ + c * CHUNK;
    int lane = threadIdx.x;
    int quad = lane >> 4, l16 = lane & 15;

    f32x4_t acc[4][4];
#pragma unroll
    for (int i = 0; i < 4; ++i)
#pragma unroll
        for (int j = 0; j < 4; ++j) acc[i][j] = (f32x4_t){0.f, 0.f, 0.f, 0.f};

#pragma unroll
    for (int ks = 0; ks < 4; ++ks) {
        bf16x8_t a[4], bb[4];
#pragma unroll
        for (int mi = 0; mi < 4; ++mi)
            a[mi] = *(const bf16x8_t*)&xBC[(size_t)(row0 + mi * 16 + l16) * CONV_CH +
                                           D_INNER + D_STATE + ks * 32 + quad * 8];
#pragma unroll
        for (int ni = 0; ni < 4; ++ni)
            bb[ni] = *(const bf16x8_t*)&xBC[(size_t)(row0 + ni * 16 + l16) * CONV_CH +
                                            D_INNER + ks * 32 + quad * 8];
#pragma unroll
        for (int mi = 0; mi < 4; ++mi)
#pragma unroll
            for (int ni = 0; ni < 4; ++ni)
                acc[mi][ni] = __builtin_amdgcn_mfma_f32_16x16x32_bf16(
                    a[mi], bb[ni], acc[mi][ni], 0, 0, 0);
    }
#pragma unroll
    for (int ni = 0; ni < 4; ++ni) {
        int s = ni * 16 + l16;
#pragma unroll
        for (int mi = 0; mi < 4; ++mi)
#pragma unroll
            for (int r = 0; r < 4; ++r) {
                int l = mi * 16 + quad * 4 + r;
                Gbuf[(size_t)bc * 4096 + l * 64 + s] = acc[mi][ni][r];
            }
    }
}

// ---------------------------------------------------------------------------
// MFMA chunk-states: S[p][n] = sum_l (x[l,p]*dt[l]*dec[l]) * B[l,n].
// Block = 4 waves = 4 heads of one (b,c); BsT (B transposed) shared.
// ---------------------------------------------------------------------------
__global__ __launch_bounds__(256) void states_mfma_kernel(const bf16* __restrict__ xBC,
                                                          const float* __restrict__ dtb,
                                                          const float* __restrict__ Acum,
                                                          bf16* __restrict__ states) {
    __shared__ __align__(16) __bf16 BsT[128 * 72];      // [n][l], stride 72 (144 B)
    __shared__ __align__(16) __bf16 xdT[4][64 * 72];    // per-wave [p][l]
    __shared__ float dtdec[4][64];
    int bcq = blockIdx.x;                 // (b*64+c)*8 + hq
    int hq = bcq & 7, bc = bcq >> 3;
    int c = bc & 63, b = bc >> 6;
    int tid = threadIdx.x, wave = tid >> 6, lane = tid & 63;
    int h = hq * 4 + wave;
    int bch = bc * 32 + h;
    int row0 = b * SEQ + c * CHUNK;
    int quad = lane >> 4, l16 = lane & 15;

    {
        float alast = Acum[(size_t)bch * 64 + 63];
        float a = Acum[(size_t)bch * 64 + lane];
        dtdec[wave][lane] = dtb[(size_t)(row0 + lane) * NHEADS + h] * expf(alast - a);
    }
    __syncthreads();
    for (int it = 0; it < 16; ++it) {
        int i2 = tid + 256 * it;
        int l = i2 >> 6;
        int n0 = (i2 & 63) * 2;
        unsigned v = *(const unsigned*)&xBC[(size_t)(row0 + l) * CONV_CH + D_INNER + n0];
        *(unsigned short*)&BsT[(n0    ) * 72 + l] = (unsigned short)(v & 0xffff);
        *(unsigned short*)&BsT[(n0 + 1) * 72 + l] = (unsigned short)(v >> 16);
    }
    for (int it = 0; it < 32; ++it) {
        int l = 2 * it + (lane >> 5);
        int p0 = (lane & 31) * 2;
        unsigned v = *(const unsigned*)&xBC[(size_t)(row0 + l) * CONV_CH + h * 64 + p0];
        float f = dtdec[wave][l];
        xdT[wave][(p0    ) * 72 + l] = tobf(bfbits2f((unsigned short)(v & 0xffff)) * f);
        xdT[wave][(p0 + 1) * 72 + l] = tobf(bfbits2f((unsigned short)(v >> 16)) * f);
    }
    __syncthreads();

    f32x4_t acc[4][8];
#pragma unroll
    for (int i = 0; i < 4; ++i)
#pragma unroll
        for (int j = 0; j < 8; ++j) acc[i][j] = (f32x4_t){0.f, 0.f, 0.f, 0.f};
#pragma unroll
    for (int ks = 0; ks < 2; ++ks) {
        bf16x8_t a[4], bb[8];
#pragma unroll
        for (int mi = 0; mi < 4; ++mi)
            a[mi] = *(const bf16x8_t*)(&xdT[wave][(mi * 16 + l16) * 72 + ks * 32 + quad * 8]);
#pragma unroll
        for (int ni = 0; ni < 8; ++ni)
            bb[ni] = *(const bf16x8_t*)(&BsT[(ni * 16 + l16) * 72 + ks * 32 + quad * 8]);
#pragma unroll
        for (int mi = 0; mi < 4; ++mi)
#pragma unroll
            for (int ni = 0; ni < 8; ++ni)
                acc[mi][ni] = __builtin_amdgcn_mfma_f32_16x16x32_bf16(
                    a[mi], bb[ni], acc[mi][ni], 0, 0, 0);
    }
#pragma unroll
    for (int ni = 0; ni < 8; ++ni) {
        int n = ni * 16 + l16;
#pragma unroll
        for (int mi = 0; mi < 4; ++mi)
#pragma unroll
            for (int r = 0; r < 4; ++r) {
                int p = mi * 16 + quad * 4 + r;
                stf(&states[(size_t)bch * 8192 + p * 128 + n], acc[mi][ni][r]);
            }
    }
}

// Inter-chunk scan (in place), 4 states/thread, fp32 carry.
__global__ void scan_kernel(const float* __restrict__ Acum,
                            bf16* __restrict__ states) {
    int i = blockIdx.x * 256 + threadIdx.x;     // BATCH*NHEADS*2048 exactly
    int pn0 = (i & 2047) * 4;
    int bh = i >> 11;
    int h = bh & 31, b = bh >> 5;
    float carry[4] = {0.f, 0.f, 0.f, 0.f};
    for (int c = 0; c < NCHUNK; ++c) {
        int bch = (b * NCHUNK + c) * NHEADS + h;
        bf16* sp = &states[(size_t)bch * 8192 + pn0];
        uint2 v = *(const uint2*)sp;
        float s0 = bfbits2f((unsigned short)(v.x & 0xffff));
        float s1 = bfbits2f((unsigned short)(v.x >> 16));
        float s2 = bfbits2f((unsigned short)(v.y & 0xffff));
        float s3 = bfbits2f((unsigned short)(v.y >> 16));
        uint2 o;
        o.x = (unsigned)bfbits(carry[0]) | ((unsigned)bfbits(carry[1]) << 16);
        o.y = (unsigned)bfbits(carry[2]) | ((unsigned)bfbits(carry[3]) << 16);
        *(uint2*)sp = o;
        float dec = expf(Acum[(size_t)bch * 64 + 63]);
        carry[0] = carry[0] * dec + s0;
        carry[1] = carry[1] * dec + s1;
        carry[2] = carry[2] * dec + s2;
        carry[3] = carry[3] * dec + s3;
    }
}

// ---------------------------------------------------------------------------
// MFMA Y: Y[l][p] = sum_s M[l][s]*x[s][p] + sum_n (C[l][n]*sdo[l])*state[p][n]
//                  + D[h]*x[l][p].   One wave per (b,c,h).  (round-5 verified)
// ---------------------------------------------------------------------------
__global__ __launch_bounds__(64) void y_mfma_kernel(const bf16* __restrict__ xBC,
                                                    const float* __restrict__ dtb,
                                                    const float* __restrict__ Acum,
                                                    const float* __restrict__ Gbuf,
                                                    const bf16* __restrict__ states,
                                                    const float* __restrict__ Dv,
                                                    bf16* __restrict__ y) {
    __shared__ __align__(16) __bf16 Mm[64 * 72];
    __shared__ __align__(16) __bf16 xsT[64 * 72];
    __shared__ float acs[64], dtss[64], sdos[64];
    int bch = blockIdx.x;
    int h = bch & 31, bc = bch >> 5;
    int c = bc & 63, b = bc >> 6;
    int row0 = b * SEQ + c * CHUNK;
    int lane = threadIdx.x;
    int quad = lane >> 4, l16 = lane & 15;

    {
        float a = Acum[(size_t)bch * 64 + lane];
        acs[lane] = a;
        sdos[lane] = expf(a);
        dtss[lane] = dtb[(size_t)(row0 + lane) * NHEADS + h];
    }
    __syncthreads();
    for (int l = 0; l < 64; ++l) {
        int s = lane;
        float d = acs[l] - acs[s];
        float g = (s <= l) ? Gbuf[(size_t)bc * 4096 + l * 64 + s] * dtss[s] : 0.f;
        float coef = g * expf((s <= l) ? d : 0.f);
        Mm[l * 72 + s] = tobf(coef);
    }
    for (int it = 0; it < 32; ++it) {
        int l = 2 * it + (lane >> 5);
        int p0 = (lane & 31) * 2;
        unsigned v = *(const unsigned*)&xBC[(size_t)(row0 + l) * CONV_CH + h * 64 + p0];
        *(unsigned short*)&xsT[(p0    ) * 72 + l] = (unsigned short)(v & 0xffff);
        *(unsigned short*)&xsT[(p0 + 1) * 72 + l] = (unsigned short)(v >> 16);
    }
    __syncthreads();

    f32x4_t acc[4][4];
#pragma unroll
    for (int i = 0; i < 4; ++i)
#pragma unroll
        for (int j = 0; j < 4; ++j) acc[i][j] = (f32x4_t){0.f, 0.f, 0.f, 0.f};

#pragma unroll
    for (int ks = 0; ks < 2; ++ks) {
        bf16x8_t a[4], bb[4];
#pragma unroll
        for (int mi = 0; mi < 4; ++mi)
            a[mi] = *(const bf16x8_t*)(&Mm[(mi * 16 + l16) * 72 + ks * 32 + quad * 8]);
#pragma unroll
        for (int ni = 0; ni < 4; ++ni)
            bb[ni] = *(const bf16x8_t*)(&xsT[(ni * 16 + l16) * 72 + ks * 32 + quad * 8]);
#pragma unroll
        for (int mi = 0; mi < 4; ++mi)
#pragma unroll
            for (int ni = 0; ni < 4; ++ni)
                acc[mi][ni] = __builtin_amdgcn_mfma_f32_16x16x32_bf16(
                    a[mi], bb[ni], acc[mi][ni], 0, 0, 0);
    }
    float sdo_mi[4];
#pragma unroll
    for (int mi = 0; mi < 4; ++mi) sdo_mi[mi] = sdos[mi * 16 + l16];
#pragma unroll
    for (int ks = 0; ks < 4; ++ks) {
        bf16x8_t a[4], bb[4];
#pragma unroll
        for (int mi = 0; mi < 4; ++mi) {
            const unsigned* cp = (const unsigned*)&xBC[(size_t)(row0 + mi * 16 + l16) * CONV_CH
                                                       + D_INNER + D_STATE + ks * 32 + quad * 8];
            float sc = sdo_mi[mi];
#pragma unroll
            for (int jj = 0; jj < 4; ++jj) {
                unsigned v = cp[jj];
                a[mi][2 * jj    ] = tobf(bfbits2f((unsigned short)(v & 0xffff)) * sc);
                a[mi][2 * jj + 1] = tobf(bfbits2f((unsigned short)(v >> 16)) * sc);
            }
        }
#pragma unroll
        for (int ni = 0; ni < 4; ++ni)
            bb[ni] = *(const bf16x8_t*)&states[(size_t)bch * 8192 + (ni * 16 + l16) * 128
                                               + ks * 32 + quad * 8];
#pragma unroll
        for (int mi = 0; mi < 4; ++mi)
#pragma unroll
            for (int ni = 0; ni < 4; ++ni)
                acc[mi][ni] = __builtin_amdgcn_mfma_f32_16x16x32_bf16(
                    a[mi], bb[ni], acc[mi][ni], 0, 0, 0);
    }
    float Dh = Dv[h];
#pragma unroll
    for (int ni = 0; ni < 4; ++ni) {
        int p = ni * 16 + l16;
#pragma unroll
        for (int mi = 0; mi < 4; ++mi)
#pragma unroll
            for (int r = 0; r < 4; ++r) {
                int l = mi * 16 + quad * 4 + r;
                float xv = bfbits2f(*(const unsigned short*)&xsT[p * 72 + l]);
                stf(&y[(size_t)(row0 + l) * D_INNER + h * 64 + p],
                    acc[mi][ni][r] + Dh * xv);
            }
    }
}

// Per row: v = y * silu(z); y = v * rsqrt(mean(v^2)+eps) * norm_w.  Vectorized:
// thread owns 8 contiguous cols (16 B loads/stores).
__global__ __launch_bounds__(256) void gate_norm_kernel(const bf16* __restrict__ Z,
                                                        const float* __restrict__ nw,
                                                        bf16* __restrict__ y) {
    int row = blockIdx.x;
    int tid = threadIdx.x;
    int col0 = tid * 8;
    uint4 zv = *(const uint4*)&Z[(size_t)row * D_INNER + col0];
    uint4 yv = *(const uint4*)&y[(size_t)row * D_INNER + col0];
    const unsigned zz[4] = {zv.x, zv.y, zv.z, zv.w};
    const unsigned yy[4] = {yv.x, yv.y, yv.z, yv.w};
    float vals[8];
    float local = 0.f;
#pragma unroll
    for (int j = 0; j < 4; ++j) {
        float z0 = bfbits2f((unsigned short)(zz[j] & 0xffff));
        float z1 = bfbits2f((unsigned short)(zz[j] >> 16));
        float y0 = bfbits2f((unsigned short)(yy[j] & 0xffff));
        float y1 = bfbits2f((unsigned short)(yy[j] >> 16));
        float v0 = y0 * siluf_(z0);
        float v1 = y1 * siluf_(z1);
        vals[2*j] = v0; vals[2*j+1] = v1;
        local += v0 * v0 + v1 * v1;
    }
#pragma unroll
    for (int off = 32; off; off >>= 1) local += __shfl_down(local, off, 64);
    __shared__ float wsum[4];
    if ((tid & 63) == 0) wsum[tid >> 6] = local;
    __syncthreads();
    float total = wsum[0] + wsum[1] + wsum[2] + wsum[3];
    float scale = rsqrtf(total / (float)D_INNER + EPS_RMS);
    float4 w0 = ((const float4*)nw)[col0 / 4];
    float4 w1 = ((const float4*)nw)[col0 / 4 + 1];
    const float ww[8] = {w0.x, w0.y, w0.z, w0.w, w1.x, w1.y, w1.z, w1.w};
    unsigned o[4];
#pragma unroll
    for (int j = 0; j < 4; ++j)
        o[j] = (unsigned)bfbits(vals[2*j] * scale * ww[2*j]) |
               ((unsigned)bfbits(vals[2*j+1] * scale * ww[2*j+1]) << 16);
    *(uint4*)&y[(size_t)row * D_INNER + col0] = make_uint4(o[0], o[1], o[2], o[3]);
}

// ---------------------------------------------------------------------------
extern "C" void kernel_launch(void* const* d_in, const int* in_sizes, int n_in,
                              void* d_out, int out_size, void* d_ws, size_t ws_size,
                              hipStream_t stream) {
    const float* u       = (const float*)d_in[0];
    const float* W_in    = (const float*)d_in[1];
    const float* conv_w  = (const float*)d_in[2];
    const float* conv_b  = (const float*)d_in[3];
    const float* dt_bias = (const float*)d_in[4];
    const float* A_log   = (const float*)d_in[5];
    const float* Dv      = (const float*)d_in[6];
    const float* norm_w  = (const float*)d_in[7];
    const float* W_out   = (const float*)d_in[8];
    float* out = (float*)d_out;

    const size_t sz_xBC    = (size_t)ROWS * CONV_CH * 2;
    const size_t sz_Z      = (size_t)ROWS * D_INNER * 2;
    const size_t sz_y      = (size_t)ROWS * D_INNER * 2;
    const size_t sz_states = (size_t)BATCH * NCHUNK * NHEADS * 8192 * 2;
    const size_t sz_dtb    = (size_t)ROWS * NHEADS * 4;
    const size_t sz_Acum   = (size_t)BATCH * NCHUNK * NHEADS * 64 * 4;
    const size_t sz_Gbuf   = (size_t)BATCH * NCHUNK * 4096 * 4;
    const size_t sz_WinT   = (size_t)WINT_ROWS * D_MODEL * 2;
    const size_t sz_WoutT  = (size_t)D_MODEL * D_INNER * 2;
    const size_t need = sz_xBC + sz_Z + sz_y + sz_states + sz_dtb + sz_Acum +
                        sz_Gbuf + sz_WinT + sz_WoutT;
    if (ws_size < need) {
        hipMemsetAsync(d_out, 0, (size_t)out_size * sizeof(float), stream);
        return;
    }
    char* ws = (char*)d_ws;
    size_t off = 0;
    bf16*  xBC    = (bf16*) (ws + off); off += sz_xBC;
    bf16*  Z      = (bf16*) (ws + off); off += sz_Z;
    bf16*  y      = (bf16*) (ws + off); off += sz_y;
    bf16*  states = (bf16*) (ws + off); off += sz_states;
    float* dtb    = (float*)(ws + off); off += sz_dtb;
    float* Acum   = (float*)(ws + off); off += sz_Acum;
    float* Gbuf   = (float*)(ws + off); off += sz_Gbuf;
    bf16*  W_inT  = (bf16*) (ws + off); off += sz_WinT;
    bf16*  W_outT = (bf16*) (ws + off); off += sz_WoutT;
    // R (38.3 MB) and u_bf16 (16.8 MB) alias states (67.1 MB); both dead
    // before states_mfma_kernel writes it.
    bf16* R      = states;
    bf16* u_bf16 = (bf16*)((char*)states + (size_t)ROWS * RCOLS * 2);

    // 0) prep
    cvt_bf16_kernel<<<(ROWS * D_MODEL / 4 + 255) / 256, 256, 0, stream>>>(
        u, u_bf16, ROWS * D_MODEL / 4);
    transpose_cvt_kernel<<<dim3(WINT_ROWS / 32, D_MODEL / 32), 256, 0, stream>>>(
        W_in, W_inT, D_MODEL, D_IN_PROJ, WINT_ROWS);
    transpose_cvt_kernel<<<dim3(D_MODEL / 32, D_INNER / 32), 256, 0, stream>>>(
        W_out, W_outT, D_INNER, D_MODEL, D_MODEL);
    // 1) GEMM1 split
    gemm_mfma_bt<bf16><<<dim3(D_INNER / 128, ROWS / 128), 256, 0, stream>>>(
        u_bf16, D_MODEL, W_inT, D_MODEL, Z, D_INNER, ROWS, D_INNER, D_MODEL);
    gemm_mfma_bt<bf16><<<dim3((RCOLS + 127) / 128, ROWS / 128), 256, 0, stream>>>(
        u_bf16, D_MODEL, W_inT + (size_t)D_INNER * D_MODEL, D_MODEL,
        R, RCOLS, ROWS, RCOLS, D_MODEL);
    // 2) conv + silu ; dt
    conv_silu_kernel<<<ROWS * 288 / 256, 256, 0, stream>>>(R, conv_w, conv_b, xBC);
    dt_kernel<<<ROWS * 4 / 256, 256, 0, stream>>>(R, dt_bias, dtb);
    // 3) per-chunk cumsum of A*dt
    acum_kernel<<<BATCH * NCHUNK * NHEADS, 64, 0, stream>>>(dtb, A_log, Acum);
    // 4) G = C @ B^T per (b,c)  (MFMA)
    gchunk_mfma_kernel<<<BATCH * NCHUNK, 64, 0, stream>>>(xBC, Gbuf);
    // 5) per-chunk states (MFMA; overwrites R/u_bf16 aliases — both dead)
    states_mfma_kernel<<<BATCH * NCHUNK * 8, 256, 0, stream>>>(xBC, dtb, Acum, states);
    // 6) inter-chunk scan (4 elems/thread)
    scan_kernel<<<BATCH * NHEADS * 2048 / 256, 256, 0, stream>>>(Acum, states);
    // 7+8) Y = diag + off + D*x  (MFMA, fused)
    y_mfma_kernel<<<BATCH * NCHUNK * NHEADS, 64, 0, stream>>>(
        xBC, dtb, Acum, Gbuf, states, Dv, y);
    // 9) gate + RMSNorm
    gate_norm_kernel<<<ROWS, 256, 0, stream>>>(Z, norm_w, y);
    // 10) out = y @ W_out
    gemm_mfma_bt<float><<<dim3(D_MODEL / 128, ROWS / 128), 256, 0, stream>>>(
        y, D_INNER, W_outT, D_INNER, out, D_MODEL, ROWS, D_MODEL, D_INNER);
}

// Round 7
// 490.927 us; speedup vs baseline: 5.1090x; 1.0570x over previous
//
#include <hip/hip_runtime.h>
#include <hip/hip_bf16.h>
#include <math.h>

#define D_MODEL   1024
#define D_STATE   128
#define HEADDIM   64
#define CHUNK     64
#define D_INNER   2048
#define NHEADS    32
#define D_IN_PROJ 4384   // 2*2048 + 2*128 + 32
#define CONV_CH   2304   // 2048 + 256
#define RCOLS     2336   // CONV_CH + NHEADS (xBC-raw + dt-raw columns)
#define WINT_ROWS 4480   // D_IN_PROJ padded so R-GEMM's 19th tile stays in-bounds
#define BATCH     2
#define SEQ       4096
#define NCHUNK    64     // SEQ / CHUNK
#define ROWS      (BATCH*SEQ)   // 8192
#define EPS_RMS   1e-5f

typedef __hip_bfloat16 bf16;
typedef __bf16 bf16x8_t __attribute__((ext_vector_type(8)));
typedef float  f32x4_t  __attribute__((ext_vector_type(4)));

__device__ __forceinline__ float siluf_(float x){ return x/(1.f+expf(-x)); }
__device__ __forceinline__ float ldf(const float* p){ return *p; }
__device__ __forceinline__ float ldf(const bf16* p){ return __bfloat162float(*p); }
__device__ __forceinline__ void  stf(float* p, float v){ *p = v; }
__device__ __forceinline__ void  stf(bf16* p, float v){ *p = __float2bfloat16(v); }

__device__ __forceinline__ __bf16 tobf(float v){
    __hip_bfloat16 t = __float2bfloat16(v);
    return *reinterpret_cast<__bf16*>(&t);
}
__device__ __forceinline__ unsigned short bfbits(float v){
    __hip_bfloat16 t = __float2bfloat16(v);
    return *reinterpret_cast<unsigned short*>(&t);
}
__device__ __forceinline__ float bfbits2f(unsigned short u){
    union { unsigned u; float f; } cv; cv.u = ((unsigned)u) << 16; return cv.f;
}

// async global->LDS, 16 B per lane; LDS dest is wave-uniform base + lane*16.
__device__ __forceinline__ void async16(const void* g, void* l) {
    __builtin_amdgcn_global_load_lds(
        (const __attribute__((address_space(1))) unsigned int*)g,
        (__attribute__((address_space(3))) unsigned int*)l, 16, 0, 0);
}

// ---------------------------------------------------------------------------
// MFMA GEMM: C[M,N] = A[M,K] @ Bt[N,K]^T.  (verified round-4 kernel, unchanged)
// mfma convention used everywhere in this file:
//   a-frag = rows of the M-by-K matrix   (lane holds row m=lane&15, k=(lane>>4)*8+j)
//   b-frag = rows of the N-by-K matrix   (same per-lane layout)
//   D[m][n]: col n = lane&15, row m = (lane>>4)*4 + reg     [m89/m91]
// ---------------------------------------------------------------------------
template <typename TC>
__global__ __launch_bounds__(256) void gemm_mfma_bt(const bf16* __restrict__ A, int lda,
                                                    const bf16* __restrict__ Bt, int ldb,
                                                    TC* __restrict__ C, int ldc,
                                                    int M, int N, int K) {
    __shared__ __align__(16) __bf16 As[128 * 32];
    __shared__ __align__(16) __bf16 Bs[128 * 32];
    const int tid  = threadIdx.x;
    const int wave = tid >> 6, lane = tid & 63;
    const int quad = lane >> 4, l16 = lane & 15;
    const int row0 = blockIdx.y * 128, col0 = blockIdx.x * 128;
    const int wr = (wave >> 1) * 64;
    const int wc = (wave & 1) * 64;

    f32x4_t acc[4][4];
#pragma unroll
    for (int i = 0; i < 4; ++i)
#pragma unroll
        for (int j = 0; j < 4; ++j) acc[i][j] = (f32x4_t){0.f, 0.f, 0.f, 0.f};

    const int ca0 = wave * 2, ca1 = wave * 2 + 1;
    const int srow = lane >> 2, scol = (lane & 3) * 8;
    const bf16* Ag0 = A  + (size_t)(row0 + ca0 * 16 + srow) * lda + scol;
    const bf16* Ag1 = A  + (size_t)(row0 + ca1 * 16 + srow) * lda + scol;
    const bf16* Bg0 = Bt + (size_t)(col0 + ca0 * 16 + srow) * ldb + scol;
    const bf16* Bg1 = Bt + (size_t)(col0 + ca1 * 16 + srow) * ldb + scol;
    __bf16* Al0 = As + ca0 * 512;
    __bf16* Al1 = As + ca1 * 512;
    __bf16* Bl0 = Bs + ca0 * 512;
    __bf16* Bl1 = Bs + ca1 * 512;

    for (int kk = 0; kk < K; kk += 32) {
        async16(Ag0 + kk, Al0);
        async16(Ag1 + kk, Al1);
        async16(Bg0 + kk, Bl0);
        async16(Bg1 + kk, Bl1);
        __syncthreads();
        bf16x8_t af[4], bfr[4];
#pragma unroll
        for (int mi = 0; mi < 4; ++mi)
            af[mi] = *(const bf16x8_t*)(As + (wr + mi * 16 + l16) * 32 + quad * 8);
#pragma unroll
        for (int ni = 0; ni < 4; ++ni)
            bfr[ni] = *(const bf16x8_t*)(Bs + (wc + ni * 16 + l16) * 32 + quad * 8);
#pragma unroll
        for (int mi = 0; mi < 4; ++mi)
#pragma unroll
            for (int ni = 0; ni < 4; ++ni)
                acc[mi][ni] = __builtin_amdgcn_mfma_f32_16x16x32_bf16(
                    af[mi], bfr[ni], acc[mi][ni], 0, 0, 0);
        __syncthreads();
    }

#pragma unroll
    for (int ni = 0; ni < 4; ++ni) {
        int gc = col0 + wc + ni * 16 + l16;
        if (gc >= N) continue;
#pragma unroll
        for (int mi = 0; mi < 4; ++mi) {
#pragma unroll
            for (int r = 0; r < 4; ++r) {
                int gr = row0 + wr + mi * 16 + quad * 4 + r;
                stf(&C[(size_t)gr * ldc + gc], acc[mi][ni][r]);
            }
        }
    }
}

// fp32 -> bf16 cast, 4 elems/thread
__global__ void cvt_bf16_kernel(const float* __restrict__ src,
                                bf16* __restrict__ dst, int n4) {
    int i = blockIdx.x * 256 + threadIdx.x;
    if (i >= n4) return;
    float4 v = ((const float4*)src)[i];
    dst[i * 4 + 0] = __float2bfloat16(v.x);
    dst[i * 4 + 1] = __float2bfloat16(v.y);
    dst[i * 4 + 2] = __float2bfloat16(v.z);
    dst[i * 4 + 3] = __float2bfloat16(v.w);
}

// Wt[c][r] = W[r][c], fp32 -> bf16.
__global__ __launch_bounds__(256) void transpose_cvt_kernel(const float* __restrict__ W,
                                                            bf16* __restrict__ Wt,
                                                            int R, int C, int Cpad) {
    __shared__ float tile[32][33];
    int c0 = blockIdx.x * 32, r0 = blockIdx.y * 32;
    int tx = threadIdx.x & 31, ty = threadIdx.x >> 5;
    for (int i = ty; i < 32; i += 8) {
        int r = r0 + i, c = c0 + tx;
        tile[i][tx] = (c < C) ? W[(size_t)r * C + c] : 0.f;
    }
    __syncthreads();
    for (int i = ty; i < 32; i += 8) {
        int c = c0 + i, r = r0 + tx;
        stf(&Wt[(size_t)c * R + r], tile[tx][i]);
    }
}

// conv_w[ch][k] fp32  ->  Wc[k][ch] bf16  (coalesced tap-major layout)
__global__ void prep_convw_kernel(const float* __restrict__ conv_w,
                                  bf16* __restrict__ Wc) {
    int i = blockIdx.x * 256 + threadIdx.x;     // CONV_CH*4 = 9216
    if (i >= CONV_CH * 4) return;
    int ch = i >> 2, k = i & 3;
    Wc[k * CONV_CH + ch] = __float2bfloat16(conv_w[ch * 4 + k]);
}

// ---------------------------------------------------------------------------
// Depthwise causal conv (k=4) + bias + SiLU.  One thread = 4 rows x 8 channels:
// 7 coalesced 16B R-row loads serve 4 outputs (tap reuse in regs); weights via
// tap-major bf16 Wc (coalesced 16B/tap).  All VMEM 16B, no gathers.
// ---------------------------------------------------------------------------
__global__ __launch_bounds__(256) void conv_silu_kernel(const bf16* __restrict__ R,
                                                        const bf16* __restrict__ Wc,
                                                        const float* __restrict__ conv_b,
                                                        bf16* __restrict__ xBC) {
    int idx = blockIdx.x * 256 + threadIdx.x;   // ROWS/4 * 288 = 589824 exactly
    int rq = idx / 288;
    int g = idx - rq * 288;
    int ch0 = g * 8;
    int row0 = rq * 4;                          // global row (b*SEQ + l0)
    int l0 = row0 & (SEQ - 1);                  // multiple of 4

    uint4 rv[7];                                // rows l0-3 .. l0+3
#pragma unroll
    for (int j = 0; j < 7; ++j) {
        int ls = l0 - 3 + j;
        rv[j] = (ls >= 0) ? *(const uint4*)&R[(size_t)(row0 - 3 + j) * RCOLS + ch0]
                          : make_uint4(0u, 0u, 0u, 0u);
    }
    uint4 wv[4];
#pragma unroll
    for (int k = 0; k < 4; ++k)
        wv[k] = *(const uint4*)&Wc[k * CONV_CH + ch0];
    float4 b0 = ((const float4*)conv_b)[ch0 / 4];
    float4 b1 = ((const float4*)conv_b)[ch0 / 4 + 1];
    const float bias[8] = {b0.x, b0.y, b0.z, b0.w, b1.x, b1.y, b1.z, b1.w};
    float wf[4][8];
#pragma unroll
    for (int k = 0; k < 4; ++k) {
        const unsigned* wp = (const unsigned*)&wv[k];
#pragma unroll
        for (int j2 = 0; j2 < 4; ++j2) {
            wf[k][2 * j2]     = bfbits2f((unsigned short)(wp[j2] & 0xffff));
            wf[k][2 * j2 + 1] = bfbits2f((unsigned short)(wp[j2] >> 16));
        }
    }
#pragma unroll
    for (int j = 0; j < 4; ++j) {               // output row row0+j
        float acc[8];
#pragma unroll
        for (int cc = 0; cc < 8; ++cc) acc[cc] = bias[cc];
#pragma unroll
        for (int k = 0; k < 4; ++k) {           // tap k reads loaded row j+k
            const unsigned* vp = (const unsigned*)&rv[j + k];
#pragma unroll
            for (int j2 = 0; j2 < 4; ++j2) {
                unsigned v = vp[j2];
                acc[2 * j2]     += wf[k][2 * j2]     * bfbits2f((unsigned short)(v & 0xffff));
                acc[2 * j2 + 1] += wf[k][2 * j2 + 1] * bfbits2f((unsigned short)(v >> 16));
            }
        }
        unsigned o[4];
#pragma unroll
        for (int j2 = 0; j2 < 4; ++j2)
            o[j2] = (unsigned)bfbits(siluf_(acc[2 * j2])) |
                    ((unsigned)bfbits(siluf_(acc[2 * j2 + 1])) << 16);
        *(uint4*)&xBC[(size_t)(row0 + j) * CONV_CH + ch0] = make_uint4(o[0], o[1], o[2], o[3]);
    }
}

// dt[row][h0..h0+7] = softplus(R[row][CONV_CH+h] + dt_bias[h]), vectorized.
__global__ void dt_kernel(const bf16* __restrict__ R,
                          const float* __restrict__ dt_bias,
                          float* __restrict__ dtb) {
    int i = blockIdx.x * 256 + threadIdx.x;         // ROWS*4 exactly
    int row = i >> 2, h0 = (i & 3) * 8;
    uint4 v = *(const uint4*)&R[(size_t)row * RCOLS + CONV_CH + h0];
    float4 bia0 = ((const float4*)dt_bias)[h0 / 4];
    float4 bia1 = ((const float4*)dt_bias)[h0 / 4 + 1];
    const unsigned vv[4] = {v.x, v.y, v.z, v.w};
    const float bb[8] = {bia0.x, bia0.y, bia0.z, bia0.w, bia1.x, bia1.y, bia1.z, bia1.w};
    float o[8];
#pragma unroll
    for (int j = 0; j < 4; ++j) {
        float a = bfbits2f((unsigned short)(vv[j] & 0xffff)) + bb[2*j];
        float c = bfbits2f((unsigned short)(vv[j] >> 16)) + bb[2*j+1];
        o[2*j]   = (a > 20.f) ? a : log1pf(expf(a));
        o[2*j+1] = (c > 20.f) ? c : log1pf(expf(c));
    }
    float* dp = &dtb[(size_t)row * NHEADS + h0];
    *(float4*)dp       = make_float4(o[0], o[1], o[2], o[3]);
    *(float4*)(dp + 4) = make_float4(o[4], o[5], o[6], o[7]);
}

// Per (b,c,h): inclusive cumsum of A[h]*dt over the 64-long chunk.
__global__ void acum_kernel(const float* __restrict__ dtb,
                            const float* __restrict__ A_log,
                            float* __restrict__ Acum) {
    int bch = blockIdx.x;
    int h = bch & 31;
    int bc = bch >> 5;
    int c = bc & 63, b = bc >> 6;
    int row0 = b * SEQ + c * CHUNK;
    __shared__ float sh[64];
    int l = threadIdx.x;
    float Ah = -expf(A_log[h]);
    sh[l] = Ah * dtb[(size_t)(row0 + l) * NHEADS + h];
    __syncthreads();
    float s = 0.f;
    for (int j = 0; j <= l; ++j) s += sh[j];
    Acum[(size_t)bch * 64 + l] = s;
}

// ---------------------------------------------------------------------------
// MFMA G-chunk: G[l][s] = sum_n C[l,n]*B[s,n].  One wave per (b,c).
// ---------------------------------------------------------------------------
__global__ __launch_bounds__(64) void gchunk_mfma_kernel(const bf16* __restrict__ xBC,
                                                         float* __restrict__ Gbuf) {
    int bc = blockIdx.x;
    int c = bc & 63, b = bc >> 6;
    int row0 = b * SEQ + c * CHUNK;
    int lane = threadIdx.x;
    int quad = lane >> 4, l16 = lane & 15;

    f32x4_t acc[4][4];
#pragma unroll
    for (int i = 0; i < 4; ++i)
#pragma unroll
        for (int j = 0; j < 4; ++j) acc[i][j] = (f32x4_t){0.f, 0.f, 0.f, 0.f};

#pragma unroll
    for (int ks = 0; ks < 4; ++ks) {
        bf16x8_t a[4], bb[4];
#pragma unroll
        for (int mi = 0; mi < 4; ++mi)
            a[mi] = *(const bf16x8_t*)&xBC[(size_t)(row0 + mi * 16 + l16) * CONV_CH +
                                           D_INNER + D_STATE + ks * 32 + quad * 8];
#pragma unroll
        for (int ni = 0; ni < 4; ++ni)
            bb[ni] = *(const bf16x8_t*)&xBC[(size_t)(row0 + ni * 16 + l16) * CONV_CH +
                                            D_INNER + ks * 32 + quad * 8];
#pragma unroll
        for (int mi = 0; mi < 4; ++mi)
#pragma unroll
            for (int ni = 0; ni < 4; ++ni)
                acc[mi][ni] = __builtin_amdgcn_mfma_f32_16x16x32_bf16(
                    a[mi], bb[ni], acc[mi][ni], 0, 0, 0);
    }
#pragma unroll
    for (int ni = 0; ni < 4; ++ni) {
        int s = ni * 16 + l16;
#pragma unroll
        for (int mi = 0; mi < 4; ++mi)
#pragma unroll
            for (int r = 0; r < 4; ++r) {
                int l = mi * 16 + quad * 4 + r;
                Gbuf[(size_t)bc * 4096 + l * 64 + s] = acc[mi][ni][r];
            }
    }
}

// ---------------------------------------------------------------------------
// MFMA chunk-states: S[p][n] = sum_l (x[l,p]*dt[l]*dec[l]) * B[l,n].
// ---------------------------------------------------------------------------
__global__ __launch_bounds__(256) void states_mfma_kernel(const bf16* __restrict__ xBC,
                                                          const float* __restrict__ dtb,
                                                          const float* __restrict__ Acum,
                                                          bf16* __restrict__ states) {
    __shared__ __align__(16) __bf16 BsT[128 * 72];      // [n][l], stride 72 (144 B)
    __shared__ __align__(16) __bf16 xdT[4][64 * 72];    // per-wave [p][l]
    __shared__ float dtdec[4][64];
    int bcq = blockIdx.x;                 // (b*64+c)*8 + hq
    int hq = bcq & 7, bc = bcq >> 3;
    int c = bc & 63, b = bc >> 6;
    int tid = threadIdx.x, wave = tid >> 6, lane = tid & 63;
    int h = hq * 4 + wave;
    int bch = bc * 32 + h;
    int row0 = b * SEQ + c * CHUNK;
    int quad = lane >> 4, l16 = lane & 15;

    {
        float alast = Acum[(size_t)bch * 64 + 63];
        float a = Acum[(size_t)bch * 64 + lane];
        dtdec[wave][lane] = dtb[(size_t)(row0 + lane) * NHEADS + h] * expf(alast - a);
    }
    __syncthreads();
    for (int it = 0; it < 16; ++it) {
        int i2 = tid + 256 * it;
        int l = i2 >> 6;
        int n0 = (i2 & 63) * 2;
        unsigned v = *(const unsigned*)&xBC[(size_t)(row0 + l) * CONV_CH + D_INNER + n0];
        *(unsigned short*)&BsT[(n0    ) * 72 + l] = (unsigned short)(v & 0xffff);
        *(unsigned short*)&BsT[(n0 + 1) * 72 + l] = (unsigned short)(v >> 16);
    }
    for (int it = 0; it < 32; ++it) {
        int l = 2 * it + (lane >> 5);
        int p0 = (lane & 31) * 2;
        unsigned v = *(const unsigned*)&xBC[(size_t)(row0 + l) * CONV_CH + h * 64 + p0];
        float f = dtdec[wave][l];
        xdT[wave][(p0    ) * 72 + l] = tobf(bfbits2f((unsigned short)(v & 0xffff)) * f);
        xdT[wave][(p0 + 1) * 72 + l] = tobf(bfbits2f((unsigned short)(v >> 16)) * f);
    }
    __syncthreads();

    f32x4_t acc[4][8];
#pragma unroll
    for (int i = 0; i < 4; ++i)
#pragma unroll
        for (int j = 0; j < 8; ++j) acc[i][j] = (f32x4_t){0.f, 0.f, 0.f, 0.f};
#pragma unroll
    for (int ks = 0; ks < 2; ++ks) {
        bf16x8_t a[4], bb[8];
#pragma unroll
        for (int mi = 0; mi < 4; ++mi)
            a[mi] = *(const bf16x8_t*)(&xdT[wave][(mi * 16 + l16) * 72 + ks * 32 + quad * 8]);
#pragma unroll
        for (int ni = 0; ni < 8; ++ni)
            bb[ni] = *(const bf16x8_t*)(&BsT[(ni * 16 + l16) * 72 + ks * 32 + quad * 8]);
#pragma unroll
        for (int mi = 0; mi < 4; ++mi)
#pragma unroll
            for (int ni = 0; ni < 8; ++ni)
                acc[mi][ni] = __builtin_amdgcn_mfma_f32_16x16x32_bf16(
                    a[mi], bb[ni], acc[mi][ni], 0, 0, 0);
    }
#pragma unroll
    for (int ni = 0; ni < 8; ++ni) {
        int n = ni * 16 + l16;
#pragma unroll
        for (int mi = 0; mi < 4; ++mi)
#pragma unroll
            for (int r = 0; r < 4; ++r) {
                int p = mi * 16 + quad * 4 + r;
                stf(&states[(size_t)bch * 8192 + p * 128 + n], acc[mi][ni][r]);
            }
    }
}

// Inter-chunk scan (in place), 4 states/thread, fp32 carry.
__global__ void scan_kernel(const float* __restrict__ Acum,
                            bf16* __restrict__ states) {
    int i = blockIdx.x * 256 + threadIdx.x;     // BATCH*NHEADS*2048 exactly
    int pn0 = (i & 2047) * 4;
    int bh = i >> 11;
    int h = bh & 31, b = bh >> 5;
    float carry[4] = {0.f, 0.f, 0.f, 0.f};
    for (int c = 0; c < NCHUNK; ++c) {
        int bch = (b * NCHUNK + c) * NHEADS + h;
        bf16* sp = &states[(size_t)bch * 8192 + pn0];
        uint2 v = *(const uint2*)sp;
        float s0 = bfbits2f((unsigned short)(v.x & 0xffff));
        float s1 = bfbits2f((unsigned short)(v.x >> 16));
        float s2 = bfbits2f((unsigned short)(v.y & 0xffff));
        float s3 = bfbits2f((unsigned short)(v.y >> 16));
        uint2 o;
        o.x = (unsigned)bfbits(carry[0]) | ((unsigned)bfbits(carry[1]) << 16);
        o.y = (unsigned)bfbits(carry[2]) | ((unsigned)bfbits(carry[3]) << 16);
        *(uint2*)sp = o;
        float dec = expf(Acum[(size_t)bch * 64 + 63]);
        carry[0] = carry[0] * dec + s0;
        carry[1] = carry[1] * dec + s1;
        carry[2] = carry[2] * dec + s2;
        carry[3] = carry[3] * dec + s3;
    }
}

// ---------------------------------------------------------------------------
// MFMA Y: Y[l][p] = sum_s M[l][s]*x[s][p] + sum_n (C[l][n]*sdo[l])*state[p][n]
//                  + D[h]*x[l][p].   One wave per (b,c,h).
// ---------------------------------------------------------------------------
__global__ __launch_bounds__(64) void y_mfma_kernel(const bf16* __restrict__ xBC,
                                                    const float* __restrict__ dtb,
                                                    const float* __restrict__ Acum,
                                                    const float* __restrict__ Gbuf,
                                                    const bf16* __restrict__ states,
                                                    const float* __restrict__ Dv,
                                                    bf16* __restrict__ y) {
    __shared__ __align__(16) __bf16 Mm[64 * 72];
    __shared__ __align__(16) __bf16 xsT[64 * 72];
    __shared__ float acs[64], dtss[64], sdos[64];
    int bch = blockIdx.x;
    int h = bch & 31, bc = bch >> 5;
    int c = bc & 63, b = bc >> 6;
    int row0 = b * SEQ + c * CHUNK;
    int lane = threadIdx.x;
    int quad = lane >> 4, l16 = lane & 15;

    {
        float a = Acum[(size_t)bch * 64 + lane];
        acs[lane] = a;
        sdos[lane] = expf(a);
        dtss[lane] = dtb[(size_t)(row0 + lane) * NHEADS + h];
    }
    __syncthreads();
    for (int l = 0; l < 64; ++l) {
        int s = lane;
        float d = acs[l] - acs[s];
        float g = (s <= l) ? Gbuf[(size_t)bc * 4096 + l * 64 + s] * dtss[s] : 0.f;
        float coef = g * expf((s <= l) ? d : 0.f);
        Mm[l * 72 + s] = tobf(coef);
    }
    for (int it = 0; it < 32; ++it) {
        int l = 2 * it + (lane >> 5);
        int p0 = (lane & 31) * 2;
        unsigned v = *(const unsigned*)&xBC[(size_t)(row0 + l) * CONV_CH + h * 64 + p0];
        *(unsigned short*)&xsT[(p0    ) * 72 + l] = (unsigned short)(v & 0xffff);
        *(unsigned short*)&xsT[(p0 + 1) * 72 + l] = (unsigned short)(v >> 16);
    }
    __syncthreads();

    f32x4_t acc[4][4];
#pragma unroll
    for (int i = 0; i < 4; ++i)
#pragma unroll
        for (int j = 0; j < 4; ++j) acc[i][j] = (f32x4_t){0.f, 0.f, 0.f, 0.f};

#pragma unroll
    for (int ks = 0; ks < 2; ++ks) {
        bf16x8_t a[4], bb[4];
#pragma unroll
        for (int mi = 0; mi < 4; ++mi)
            a[mi] = *(const bf16x8_t*)(&Mm[(mi * 16 + l16) * 72 + ks * 32 + quad * 8]);
#pragma unroll
        for (int ni = 0; ni < 4; ++ni)
            bb[ni] = *(const bf16x8_t*)(&xsT[(ni * 16 + l16) * 72 + ks * 32 + quad * 8]);
#pragma unroll
        for (int mi = 0; mi < 4; ++mi)
#pragma unroll
            for (int ni = 0; ni < 4; ++ni)
                acc[mi][ni] = __builtin_amdgcn_mfma_f32_16x16x32_bf16(
                    a[mi], bb[ni], acc[mi][ni], 0, 0, 0);
    }
    float sdo_mi[4];
#pragma unroll
    for (int mi = 0; mi < 4; ++mi) sdo_mi[mi] = sdos[mi * 16 + l16];
#pragma unroll
    for (int ks = 0; ks < 4; ++ks) {
        bf16x8_t a[4], bb[4];
#pragma unroll
        for (int mi = 0; mi < 4; ++mi) {
            const unsigned* cp = (const unsigned*)&xBC[(size_t)(row0 + mi * 16 + l16) * CONV_CH
                                                       + D_INNER + D_STATE + ks * 32 + quad * 8];
            float sc = sdo_mi[mi];
#pragma unroll
            for (int jj = 0; jj < 4; ++jj) {
                unsigned v = cp[jj];
                a[mi][2 * jj    ] = tobf(bfbits2f((unsigned short)(v & 0xffff)) * sc);
                a[mi][2 * jj + 1] = tobf(bfbits2f((unsigned short)(v >> 16)) * sc);
            }
        }
#pragma unroll
        for (int ni = 0; ni < 4; ++ni)
            bb[ni] = *(const bf16x8_t*)&states[(size_t)bch * 8192 + (ni * 16 + l16) * 128
                                               + ks * 32 + quad * 8];
#pragma unroll
        for (int mi = 0; mi < 4; ++mi)
#pragma unroll
            for (int ni = 0; ni < 4; ++ni)
                acc[mi][ni] = __builtin_amdgcn_mfma_f32_16x16x32_bf16(
                    a[mi], bb[ni], acc[mi][ni], 0, 0, 0);
    }
    float Dh = Dv[h];
#pragma unroll
    for (int ni = 0; ni < 4; ++ni) {
        int p = ni * 16 + l16;
#pragma unroll
        for (int mi = 0; mi < 4; ++mi)
#pragma unroll
            for (int r = 0; r < 4; ++r) {
                int l = mi * 16 + quad * 4 + r;
                float xv = bfbits2f(*(const unsigned short*)&xsT[p * 72 + l]);
                stf(&y[(size_t)(row0 + l) * D_INNER + h * 64 + p],
                    acc[mi][ni][r] + Dh * xv);
            }
    }
}

// Per row: v = y * silu(z); y = v * rsqrt(mean(v^2)+eps) * norm_w.
__global__ __launch_bounds__(256) void gate_norm_kernel(const bf16* __restrict__ Z,
                                                        const float* __restrict__ nw,
                                                        bf16* __restrict__ y) {
    int row = blockIdx.x;
    int tid = threadIdx.x;
    int col0 = tid * 8;
    uint4 zv = *(const uint4*)&Z[(size_t)row * D_INNER + col0];
    uint4 yv = *(const uint4*)&y[(size_t)row * D_INNER + col0];
    const unsigned zz[4] = {zv.x, zv.y, zv.z, zv.w};
    const unsigned yy[4] = {yv.x, yv.y, yv.z, yv.w};
    float vals[8];
    float local = 0.f;
#pragma unroll
    for (int j = 0; j < 4; ++j) {
        float z0 = bfbits2f((unsigned short)(zz[j] & 0xffff));
        float z1 = bfbits2f((unsigned short)(zz[j] >> 16));
        float y0 = bfbits2f((unsigned short)(yy[j] & 0xffff));
        float y1 = bfbits2f((unsigned short)(yy[j] >> 16));
        float v0 = y0 * siluf_(z0);
        float v1 = y1 * siluf_(z1);
        vals[2*j] = v0; vals[2*j+1] = v1;
        local += v0 * v0 + v1 * v1;
    }
#pragma unroll
    for (int off = 32; off; off >>= 1) local += __shfl_down(local, off, 64);
    __shared__ float wsum[4];
    if ((tid & 63) == 0) wsum[tid >> 6] = local;
    __syncthreads();
    float total = wsum[0] + wsum[1] + wsum[2] + wsum[3];
    float scale = rsqrtf(total / (float)D_INNER + EPS_RMS);
    float4 w0 = ((const float4*)nw)[col0 / 4];
    float4 w1 = ((const float4*)nw)[col0 / 4 + 1];
    const float ww[8] = {w0.x, w0.y, w0.z, w0.w, w1.x, w1.y, w1.z, w1.w};
    unsigned o[4];
#pragma unroll
    for (int j = 0; j < 4; ++j)
        o[j] = (unsigned)bfbits(vals[2*j] * scale * ww[2*j]) |
               ((unsigned)bfbits(vals[2*j+1] * scale * ww[2*j+1]) << 16);
    *(uint4*)&y[(size_t)row * D_INNER + col0] = make_uint4(o[0], o[1], o[2], o[3]);
}

// ---------------------------------------------------------------------------
extern "C" void kernel_launch(void* const* d_in, const int* in_sizes, int n_in,
                              void* d_out, int out_size, void* d_ws, size_t ws_size,
                              hipStream_t stream) {
    const float* u       = (const float*)d_in[0];
    const float* W_in    = (const float*)d_in[1];
    const float* conv_w  = (const float*)d_in[2];
    const float* conv_b  = (const float*)d_in[3];
    const float* dt_bias = (const float*)d_in[4];
    const float* A_log   = (const float*)d_in[5];
    const float* Dv      = (const float*)d_in[6];
    const float* norm_w  = (const float*)d_in[7];
    const float* W_out   = (const float*)d_in[8];
    float* out = (float*)d_out;

    const size_t sz_xBC    = (size_t)ROWS * CONV_CH * 2;
    const size_t sz_Z      = (size_t)ROWS * D_INNER * 2;
    const size_t sz_y      = (size_t)ROWS * D_INNER * 2;
    const size_t sz_states = (size_t)BATCH * NCHUNK * NHEADS * 8192 * 2;
    const size_t sz_dtb    = (size_t)ROWS * NHEADS * 4;
    const size_t sz_Acum   = (size_t)BATCH * NCHUNK * NHEADS * 64 * 4;
    const size_t sz_Gbuf   = (size_t)BATCH * NCHUNK * 4096 * 4;
    const size_t sz_WinT   = (size_t)WINT_ROWS * D_MODEL * 2;
    const size_t sz_WoutT  = (size_t)D_MODEL * D_INNER * 2;
    const size_t sz_Wc     = (size_t)CONV_CH * 4 * 2;
    const size_t need = sz_xBC + sz_Z + sz_y + sz_states + sz_dtb + sz_Acum +
                        sz_Gbuf + sz_WinT + sz_WoutT + sz_Wc;
    if (ws_size < need) {
        hipMemsetAsync(d_out, 0, (size_t)out_size * sizeof(float), stream);
        return;
    }
    char* ws = (char*)d_ws;
    size_t off = 0;
    bf16*  xBC    = (bf16*) (ws + off); off += sz_xBC;
    bf16*  Z      = (bf16*) (ws + off); off += sz_Z;
    bf16*  y      = (bf16*) (ws + off); off += sz_y;
    bf16*  states = (bf16*) (ws + off); off += sz_states;
    float* dtb    = (float*)(ws + off); off += sz_dtb;
    float* Acum   = (float*)(ws + off); off += sz_Acum;
    float* Gbuf   = (float*)(ws + off); off += sz_Gbuf;
    bf16*  W_inT  = (bf16*) (ws + off); off += sz_WinT;
    bf16*  W_outT = (bf16*) (ws + off); off += sz_WoutT;
    bf16*  Wc     = (bf16*) (ws + off); off += sz_Wc;
    // R (38.3 MB) and u_bf16 (16.8 MB) alias states (67.1 MB); both dead
    // before states_mfma_kernel writes it.
    bf16* R      = states;
    bf16* u_bf16 = (bf16*)((char*)states + (size_t)ROWS * RCOLS * 2);

    // 0) prep
    cvt_bf16_kernel<<<(ROWS * D_MODEL / 4 + 255) / 256, 256, 0, stream>>>(
        u, u_bf16, ROWS * D_MODEL / 4);
    transpose_cvt_kernel<<<dim3(WINT_ROWS / 32, D_MODEL / 32), 256, 0, stream>>>(
        W_in, W_inT, D_MODEL, D_IN_PROJ, WINT_ROWS);
    transpose_cvt_kernel<<<dim3(D_MODEL / 32, D_INNER / 32), 256, 0, stream>>>(
        W_out, W_outT, D_INNER, D_MODEL, D_MODEL);
    prep_convw_kernel<<<(CONV_CH * 4 + 255) / 256, 256, 0, stream>>>(conv_w, Wc);
    // 1) GEMM1 split
    gemm_mfma_bt<bf16><<<dim3(D_INNER / 128, ROWS / 128), 256, 0, stream>>>(
        u_bf16, D_MODEL, W_inT, D_MODEL, Z, D_INNER, ROWS, D_INNER, D_MODEL);
    gemm_mfma_bt<bf16><<<dim3((RCOLS + 127) / 128, ROWS / 128), 256, 0, stream>>>(
        u_bf16, D_MODEL, W_inT + (size_t)D_INNER * D_MODEL, D_MODEL,
        R, RCOLS, ROWS, RCOLS, D_MODEL);
    // 2) conv + silu (4 rows/thread) ; dt
    conv_silu_kernel<<<ROWS / 4 * 288 / 256, 256, 0, stream>>>(R, Wc, conv_b, xBC);
    dt_kernel<<<ROWS * 4 / 256, 256, 0, stream>>>(R, dt_bias, dtb);
    // 3) per-chunk cumsum of A*dt
    acum_kernel<<<BATCH * NCHUNK * NHEADS, 64, 0, stream>>>(dtb, A_log, Acum);
    // 4) G = C @ B^T per (b,c)  (MFMA)
    gchunk_mfma_kernel<<<BATCH * NCHUNK, 64, 0, stream>>>(xBC, Gbuf);
    // 5) per-chunk states (MFMA; overwrites R/u_bf16 aliases — both dead)
    states_mfma_kernel<<<BATCH * NCHUNK * 8, 256, 0, stream>>>(xBC, dtb, Acum, states);
    // 6) inter-chunk scan (4 elems/thread)
    scan_kernel<<<BATCH * NHEADS * 2048 / 256, 256, 0, stream>>>(Acum, states);
    // 7+8) Y = diag + off + D*x  (MFMA, fused)
    y_mfma_kernel<<<BATCH * NCHUNK * NHEADS, 64, 0, stream>>>(
        xBC, dtb, Acum, Gbuf, states, Dv, y);
    // 9) gate + RMSNorm
    gate_norm_kernel<<<ROWS, 256, 0, stream>>>(Z, norm_w, y);
    // 10) out = y @ W_out
    gemm_mfma_bt<float><<<dim3(D_MODEL / 128, ROWS / 128), 256, 0, stream>>>(
        y, D_INNER, W_outT, D_INNER, out, D_MODEL, ROWS, D_MODEL, D_INNER);
}

// Round 8
// 459.087 us; speedup vs baseline: 5.4634x; 1.0694x over previous
//
#include <hip/hip_runtime.h>
#include <hip/hip_bf16.h>
#include <math.h>

#define D_MODEL   1024
#define D_STATE   128
#define HEADDIM   64
#define CHUNK     64
#define D_INNER   2048
#define NHEADS    32
#define D_IN_PROJ 4384   // 2*2048 + 2*128 + 32
#define CONV_CH   2304   // 2048 + 256
#define RCOLS     2336   // CONV_CH + NHEADS (xBC-raw + dt-raw columns)
#define WINT_ROWS 4480   // D_IN_PROJ padded so col-tile 34 stays in-bounds
#define BATCH     2
#define SEQ       4096
#define NCHUNK    64     // SEQ / CHUNK
#define ROWS      (BATCH*SEQ)   // 8192
#define EPS_RMS   1e-5f

typedef __hip_bfloat16 bf16;
typedef __bf16 bf16x8_t __attribute__((ext_vector_type(8)));
typedef float  f32x4_t  __attribute__((ext_vector_type(4)));

__device__ __forceinline__ float siluf_(float x){ return x/(1.f+expf(-x)); }
__device__ __forceinline__ float ldf(const float* p){ return *p; }
__device__ __forceinline__ float ldf(const bf16* p){ return __bfloat162float(*p); }
__device__ __forceinline__ void  stf(float* p, float v){ *p = v; }
__device__ __forceinline__ void  stf(bf16* p, float v){ *p = __float2bfloat16(v); }

__device__ __forceinline__ __bf16 tobf(float v){
    __hip_bfloat16 t = __float2bfloat16(v);
    return *reinterpret_cast<__bf16*>(&t);
}
__device__ __forceinline__ unsigned short bfbits(float v){
    __hip_bfloat16 t = __float2bfloat16(v);
    return *reinterpret_cast<unsigned short*>(&t);
}
__device__ __forceinline__ float bfbits2f(unsigned short u){
    union { unsigned u; float f; } cv; cv.u = ((unsigned)u) << 16; return cv.f;
}

// async global->LDS, 16 B per lane; LDS dest is wave-uniform base + lane*16.
__device__ __forceinline__ void async16(const void* g, void* l) {
    __builtin_amdgcn_global_load_lds(
        (const __attribute__((address_space(1))) unsigned int*)g,
        (__attribute__((address_space(3))) unsigned int*)l, 16, 0, 0);
}

// ---------------------------------------------------------------------------
// Shared MFMA K-loop body (m97 structure): 128x128 tile, BK=32, 4 waves,
// wave = 64x64 patch = 4x4 of 16x16x32 tiles.
//   a-frag = rows of M-by-K, b-frag = rows of N-by-K (lane: row=lane&15,
//   k=(lane>>4)*8+j);  D[m][n]: col n = lane&15, row m = (lane>>4)*4+reg.
// ---------------------------------------------------------------------------
struct GemmCore {
    f32x4_t acc[4][4];
    __device__ __forceinline__ void run(const bf16* __restrict__ A, int lda,
                                        const bf16* __restrict__ Bt, int ldb,
                                        int row0, int col0, int k0, int k1,
                                        __bf16* As, __bf16* Bs,
                                        int wave, int lane) {
        const int quad = lane >> 4, l16 = lane & 15;
        const int wr = (wave >> 1) * 64, wc = (wave & 1) * 64;
#pragma unroll
        for (int i = 0; i < 4; ++i)
#pragma unroll
            for (int j = 0; j < 4; ++j) acc[i][j] = (f32x4_t){0.f, 0.f, 0.f, 0.f};
        const int ca0 = wave * 2, ca1 = wave * 2 + 1;
        const int srow = lane >> 2, scol = (lane & 3) * 8;
        const bf16* Ag0 = A  + (size_t)(row0 + ca0 * 16 + srow) * lda + scol;
        const bf16* Ag1 = A  + (size_t)(row0 + ca1 * 16 + srow) * lda + scol;
        const bf16* Bg0 = Bt + (size_t)(col0 + ca0 * 16 + srow) * ldb + scol;
        const bf16* Bg1 = Bt + (size_t)(col0 + ca1 * 16 + srow) * ldb + scol;
        __bf16* Al0 = As + ca0 * 512;
        __bf16* Al1 = As + ca1 * 512;
        __bf16* Bl0 = Bs + ca0 * 512;
        __bf16* Bl1 = Bs + ca1 * 512;
        for (int kk = k0; kk < k1; kk += 32) {
            async16(Ag0 + kk, Al0);
            async16(Ag1 + kk, Al1);
            async16(Bg0 + kk, Bl0);
            async16(Bg1 + kk, Bl1);
            __syncthreads();
            bf16x8_t af[4], bfr[4];
#pragma unroll
            for (int mi = 0; mi < 4; ++mi)
                af[mi] = *(const bf16x8_t*)(As + (wr + mi * 16 + l16) * 32 + quad * 8);
#pragma unroll
            for (int ni = 0; ni < 4; ++ni)
                bfr[ni] = *(const bf16x8_t*)(Bs + (wc + ni * 16 + l16) * 32 + quad * 8);
#pragma unroll
            for (int mi = 0; mi < 4; ++mi)
#pragma unroll
                for (int ni = 0; ni < 4; ++ni)
                    acc[mi][ni] = __builtin_amdgcn_mfma_f32_16x16x32_bf16(
                        af[mi], bfr[ni], acc[mi][ni], 0, 0, 0);
            __syncthreads();
        }
    }
};

// Fused Z|R GEMM: one dispatch over all 35 col-tiles of W_inT.
// grid = (64 row-tiles, 35 col-tiles); consecutive blocks share the B tile.
__global__ __launch_bounds__(256) void gemm_zr_fused(const bf16* __restrict__ A,
                                                     const bf16* __restrict__ Bt,
                                                     bf16* __restrict__ Z,
                                                     bf16* __restrict__ R) {
    __shared__ __align__(16) __bf16 As[128 * 32];
    __shared__ __align__(16) __bf16 Bs[128 * 32];
    const int tid = threadIdx.x, wave = tid >> 6, lane = tid & 63;
    const int quad = lane >> 4, l16 = lane & 15;
    const int row0 = blockIdx.x * 128;
    const int ct   = blockIdx.y;
    GemmCore g;
    g.run(A, D_MODEL, Bt, D_MODEL, row0, ct * 128, 0, D_MODEL, As, Bs, wave, lane);

    bf16* Cp; int ldc_, cl0, ncols;
    if (ct < 16) { Cp = Z; ldc_ = D_INNER; cl0 = ct * 128;          ncols = D_INNER; }
    else         { Cp = R; ldc_ = RCOLS;   cl0 = ct * 128 - D_INNER; ncols = RCOLS; }
    const int wr = (wave >> 1) * 64, wc = (wave & 1) * 64;
#pragma unroll
    for (int ni = 0; ni < 4; ++ni) {
        int gc = cl0 + wc + ni * 16 + l16;
        if (gc >= ncols) continue;
#pragma unroll
        for (int mi = 0; mi < 4; ++mi)
#pragma unroll
            for (int r = 0; r < 4; ++r) {
                int gr = row0 + wr + mi * 16 + quad * 4 + r;
                stf(&Cp[(size_t)gr * ldc_ + gc], g.acc[mi][ni][r]);
            }
    }
}

// Out GEMM, split-K=2: partial[kz][m][n] fp32.  grid = (64, 8, 2).
__global__ __launch_bounds__(256) void gemm_out_splitk(const bf16* __restrict__ A,
                                                       const bf16* __restrict__ Bt,
                                                       float* __restrict__ part) {
    __shared__ __align__(16) __bf16 As[128 * 32];
    __shared__ __align__(16) __bf16 Bs[128 * 32];
    const int tid = threadIdx.x, wave = tid >> 6, lane = tid & 63;
    const int quad = lane >> 4, l16 = lane & 15;
    const int row0 = blockIdx.x * 128;
    const int col0 = blockIdx.y * 128;
    const int kz   = blockIdx.z;
    GemmCore g;
    g.run(A, D_INNER, Bt, D_INNER, row0, col0, kz * 1024, kz * 1024 + 1024,
          As, Bs, wave, lane);
    float* P = part + (size_t)kz * ROWS * D_MODEL;
    const int wr = (wave >> 1) * 64, wc = (wave & 1) * 64;
#pragma unroll
    for (int ni = 0; ni < 4; ++ni) {
        int gc = col0 + wc + ni * 16 + l16;
#pragma unroll
        for (int mi = 0; mi < 4; ++mi)
#pragma unroll
            for (int r = 0; r < 4; ++r) {
                int gr = row0 + wr + mi * 16 + quad * 4 + r;
                P[(size_t)gr * D_MODEL + gc] = g.acc[mi][ni][r];
            }
    }
}

// out = part0 + part1  (float4 vectorized)
__global__ void reduce_out_kernel(const float* __restrict__ part,
                                  float* __restrict__ out) {
    int i = blockIdx.x * 256 + threadIdx.x;     // ROWS*D_MODEL/4 exactly
    float4 a = ((const float4*)part)[i];
    float4 b = ((const float4*)(part + (size_t)ROWS * D_MODEL))[i];
    ((float4*)out)[i] = make_float4(a.x + b.x, a.y + b.y, a.z + b.z, a.w + b.w);
}

// fp32 -> bf16 cast, 4 elems/thread
__global__ void cvt_bf16_kernel(const float* __restrict__ src,
                                bf16* __restrict__ dst, int n4) {
    int i = blockIdx.x * 256 + threadIdx.x;
    if (i >= n4) return;
    float4 v = ((const float4*)src)[i];
    dst[i * 4 + 0] = __float2bfloat16(v.x);
    dst[i * 4 + 1] = __float2bfloat16(v.y);
    dst[i * 4 + 2] = __float2bfloat16(v.z);
    dst[i * 4 + 3] = __float2bfloat16(v.w);
}

// Wt[c][r] = W[r][c], fp32 -> bf16.
__global__ __launch_bounds__(256) void transpose_cvt_kernel(const float* __restrict__ W,
                                                            bf16* __restrict__ Wt,
                                                            int R, int C, int Cpad) {
    __shared__ float tile[32][33];
    int c0 = blockIdx.x * 32, r0 = blockIdx.y * 32;
    int tx = threadIdx.x & 31, ty = threadIdx.x >> 5;
    for (int i = ty; i < 32; i += 8) {
        int r = r0 + i, c = c0 + tx;
        tile[i][tx] = (c < C) ? W[(size_t)r * C + c] : 0.f;
    }
    __syncthreads();
    for (int i = ty; i < 32; i += 8) {
        int c = c0 + i, r = r0 + tx;
        stf(&Wt[(size_t)c * R + r], tile[tx][i]);
    }
}

// conv_w[ch][k] fp32  ->  Wc[k][ch] bf16  (coalesced tap-major layout)
__global__ void prep_convw_kernel(const float* __restrict__ conv_w,
                                  bf16* __restrict__ Wc) {
    int i = blockIdx.x * 256 + threadIdx.x;     // CONV_CH*4 = 9216
    if (i >= CONV_CH * 4) return;
    int ch = i >> 2, k = i & 3;
    Wc[k * CONV_CH + ch] = __float2bfloat16(conv_w[ch * 4 + k]);
}

// ---------------------------------------------------------------------------
// Depthwise causal conv (k=4) + bias + SiLU.  One thread = 4 rows x 8 channels.
// ---------------------------------------------------------------------------
__global__ __launch_bounds__(256) void conv_silu_kernel(const bf16* __restrict__ R,
                                                        const bf16* __restrict__ Wc,
                                                        const float* __restrict__ conv_b,
                                                        bf16* __restrict__ xBC) {
    int idx = blockIdx.x * 256 + threadIdx.x;   // ROWS/4 * 288 exactly
    int rq = idx / 288;
    int g = idx - rq * 288;
    int ch0 = g * 8;
    int row0 = rq * 4;
    int l0 = row0 & (SEQ - 1);

    uint4 rv[7];
#pragma unroll
    for (int j = 0; j < 7; ++j) {
        int ls = l0 - 3 + j;
        rv[j] = (ls >= 0) ? *(const uint4*)&R[(size_t)(row0 - 3 + j) * RCOLS + ch0]
                          : make_uint4(0u, 0u, 0u, 0u);
    }
    uint4 wv[4];
#pragma unroll
    for (int k = 0; k < 4; ++k)
        wv[k] = *(const uint4*)&Wc[k * CONV_CH + ch0];
    float4 b0 = ((const float4*)conv_b)[ch0 / 4];
    float4 b1 = ((const float4*)conv_b)[ch0 / 4 + 1];
    const float bias[8] = {b0.x, b0.y, b0.z, b0.w, b1.x, b1.y, b1.z, b1.w};
    float wf[4][8];
#pragma unroll
    for (int k = 0; k < 4; ++k) {
        const unsigned* wp = (const unsigned*)&wv[k];
#pragma unroll
        for (int j2 = 0; j2 < 4; ++j2) {
            wf[k][2 * j2]     = bfbits2f((unsigned short)(wp[j2] & 0xffff));
            wf[k][2 * j2 + 1] = bfbits2f((unsigned short)(wp[j2] >> 16));
        }
    }
#pragma unroll
    for (int j = 0; j < 4; ++j) {
        float acc[8];
#pragma unroll
        for (int cc = 0; cc < 8; ++cc) acc[cc] = bias[cc];
#pragma unroll
        for (int k = 0; k < 4; ++k) {
            const unsigned* vp = (const unsigned*)&rv[j + k];
#pragma unroll
            for (int j2 = 0; j2 < 4; ++j2) {
                unsigned v = vp[j2];
                acc[2 * j2]     += wf[k][2 * j2]     * bfbits2f((unsigned short)(v & 0xffff));
                acc[2 * j2 + 1] += wf[k][2 * j2 + 1] * bfbits2f((unsigned short)(v >> 16));
            }
        }
        unsigned o[4];
#pragma unroll
        for (int j2 = 0; j2 < 4; ++j2)
            o[j2] = (unsigned)bfbits(siluf_(acc[2 * j2])) |
                    ((unsigned)bfbits(siluf_(acc[2 * j2 + 1])) << 16);
        *(uint4*)&xBC[(size_t)(row0 + j) * CONV_CH + ch0] = make_uint4(o[0], o[1], o[2], o[3]);
    }
}

// dt[row][h0..h0+7] = softplus(R[row][CONV_CH+h] + dt_bias[h]), vectorized.
__global__ void dt_kernel(const bf16* __restrict__ R,
                          const float* __restrict__ dt_bias,
                          float* __restrict__ dtb) {
    int i = blockIdx.x * 256 + threadIdx.x;         // ROWS*4 exactly
    int row = i >> 2, h0 = (i & 3) * 8;
    uint4 v = *(const uint4*)&R[(size_t)row * RCOLS + CONV_CH + h0];
    float4 bia0 = ((const float4*)dt_bias)[h0 / 4];
    float4 bia1 = ((const float4*)dt_bias)[h0 / 4 + 1];
    const unsigned vv[4] = {v.x, v.y, v.z, v.w};
    const float bb[8] = {bia0.x, bia0.y, bia0.z, bia0.w, bia1.x, bia1.y, bia1.z, bia1.w};
    float o[8];
#pragma unroll
    for (int j = 0; j < 4; ++j) {
        float a = bfbits2f((unsigned short)(vv[j] & 0xffff)) + bb[2*j];
        float c = bfbits2f((unsigned short)(vv[j] >> 16)) + bb[2*j+1];
        o[2*j]   = (a > 20.f) ? a : log1pf(expf(a));
        o[2*j+1] = (c > 20.f) ? c : log1pf(expf(c));
    }
    float* dp = &dtb[(size_t)row * NHEADS + h0];
    *(float4*)dp       = make_float4(o[0], o[1], o[2], o[3]);
    *(float4*)(dp + 4) = make_float4(o[4], o[5], o[6], o[7]);
}

// Per (b,c,h): inclusive cumsum of A[h]*dt over the 64-long chunk.
__global__ void acum_kernel(const float* __restrict__ dtb,
                            const float* __restrict__ A_log,
                            float* __restrict__ Acum) {
    int bch = blockIdx.x;
    int h = bch & 31;
    int bc = bch >> 5;
    int c = bc & 63, b = bc >> 6;
    int row0 = b * SEQ + c * CHUNK;
    __shared__ float sh[64];
    int l = threadIdx.x;
    float Ah = -expf(A_log[h]);
    sh[l] = Ah * dtb[(size_t)(row0 + l) * NHEADS + h];
    __syncthreads();
    float s = 0.f;
    for (int j = 0; j <= l; ++j) s += sh[j];
    Acum[(size_t)bch * 64 + l] = s;
}

// ---------------------------------------------------------------------------
// MFMA G-chunk: G[l][s] = sum_n C[l,n]*B[s,n].  One wave per (b,c).
// ---------------------------------------------------------------------------
__global__ __launch_bounds__(64) void gchunk_mfma_kernel(const bf16* __restrict__ xBC,
                                                         float* __restrict__ Gbuf) {
    int bc = blockIdx.x;
    int c = bc & 63, b = bc >> 6;
    int row0 = b * SEQ + c * CHUNK;
    int lane = threadIdx.x;
    int quad = lane >> 4, l16 = lane & 15;

    f32x4_t acc[4][4];
#pragma unroll
    for (int i = 0; i < 4; ++i)
#pragma unroll
        for (int j = 0; j < 4; ++j) acc[i][j] = (f32x4_t){0.f, 0.f, 0.f, 0.f};

#pragma unroll
    for (int ks = 0; ks < 4; ++ks) {
        bf16x8_t a[4], bb[4];
#pragma unroll
        for (int mi = 0; mi < 4; ++mi)
            a[mi] = *(const bf16x8_t*)&xBC[(size_t)(row0 + mi * 16 + l16) * CONV_CH +
                                           D_INNER + D_STATE + ks * 32 + quad * 8];
#pragma unroll
        for (int ni = 0; ni < 4; ++ni)
            bb[ni] = *(const bf16x8_t*)&xBC[(size_t)(row0 + ni * 16 + l16) * CONV_CH +
                                            D_INNER + ks * 32 + quad * 8];
#pragma unroll
        for (int mi = 0; mi < 4; ++mi)
#pragma unroll
            for (int ni = 0; ni < 4; ++ni)
                acc[mi][ni] = __builtin_amdgcn_mfma_f32_16x16x32_bf16(
                    a[mi], bb[ni], acc[mi][ni], 0, 0, 0);
    }
#pragma unroll
    for (int ni = 0; ni < 4; ++ni) {
        int s = ni * 16 + l16;
#pragma unroll
        for (int mi = 0; mi < 4; ++mi)
#pragma unroll
            for (int r = 0; r < 4; ++r) {
                int l = mi * 16 + quad * 4 + r;
                Gbuf[(size_t)bc * 4096 + l * 64 + s] = acc[mi][ni][r];
            }
    }
}

// ---------------------------------------------------------------------------
// MFMA chunk-states: S[p][n] = sum_l (x[l,p]*dt[l]*dec[l]) * B[l,n].
// ---------------------------------------------------------------------------
__global__ __launch_bounds__(256) void states_mfma_kernel(const bf16* __restrict__ xBC,
                                                          const float* __restrict__ dtb,
                                                          const float* __restrict__ Acum,
                                                          bf16* __restrict__ states) {
    __shared__ __align__(16) __bf16 BsT[128 * 72];      // [n][l], stride 72 (144 B)
    __shared__ __align__(16) __bf16 xdT[4][64 * 72];    // per-wave [p][l]
    __shared__ float dtdec[4][64];
    int bcq = blockIdx.x;                 // (b*64+c)*8 + hq
    int hq = bcq & 7, bc = bcq >> 3;
    int c = bc & 63, b = bc >> 6;
    int tid = threadIdx.x, wave = tid >> 6, lane = tid & 63;
    int h = hq * 4 + wave;
    int bch = bc * 32 + h;
    int row0 = b * SEQ + c * CHUNK;
    int quad = lane >> 4, l16 = lane & 15;

    {
        float alast = Acum[(size_t)bch * 64 + 63];
        float a = Acum[(size_t)bch * 64 + lane];
        dtdec[wave][lane] = dtb[(size_t)(row0 + lane) * NHEADS + h] * expf(alast - a);
    }
    __syncthreads();
    for (int it = 0; it < 16; ++it) {
        int i2 = tid + 256 * it;
        int l = i2 >> 6;
        int n0 = (i2 & 63) * 2;
        unsigned v = *(const unsigned*)&xBC[(size_t)(row0 + l) * CONV_CH + D_INNER + n0];
        *(unsigned short*)&BsT[(n0    ) * 72 + l] = (unsigned short)(v & 0xffff);
        *(unsigned short*)&BsT[(n0 + 1) * 72 + l] = (unsigned short)(v >> 16);
    }
    for (int it = 0; it < 32; ++it) {
        int l = 2 * it + (lane >> 5);
        int p0 = (lane & 31) * 2;
        unsigned v = *(const unsigned*)&xBC[(size_t)(row0 + l) * CONV_CH + h * 64 + p0];
        float f = dtdec[wave][l];
        xdT[wave][(p0    ) * 72 + l] = tobf(bfbits2f((unsigned short)(v & 0xffff)) * f);
        xdT[wave][(p0 + 1) * 72 + l] = tobf(bfbits2f((unsigned short)(v >> 16)) * f);
    }
    __syncthreads();

    f32x4_t acc[4][8];
#pragma unroll
    for (int i = 0; i < 4; ++i)
#pragma unroll
        for (int j = 0; j < 8; ++j) acc[i][j] = (f32x4_t){0.f, 0.f, 0.f, 0.f};
#pragma unroll
    for (int ks = 0; ks < 2; ++ks) {
        bf16x8_t a[4], bb[8];
#pragma unroll
        for (int mi = 0; mi < 4; ++mi)
            a[mi] = *(const bf16x8_t*)(&xdT[wave][(mi * 16 + l16) * 72 + ks * 32 + quad * 8]);
#pragma unroll
        for (int ni = 0; ni < 8; ++ni)
            bb[ni] = *(const bf16x8_t*)(&BsT[(ni * 16 + l16) * 72 + ks * 32 + quad * 8]);
#pragma unroll
        for (int mi = 0; mi < 4; ++mi)
#pragma unroll
            for (int ni = 0; ni < 8; ++ni)
                acc[mi][ni] = __builtin_amdgcn_mfma_f32_16x16x32_bf16(
                    a[mi], bb[ni], acc[mi][ni], 0, 0, 0);
    }
#pragma unroll
    for (int ni = 0; ni < 8; ++ni) {
        int n = ni * 16 + l16;
#pragma unroll
        for (int mi = 0; mi < 4; ++mi)
#pragma unroll
            for (int r = 0; r < 4; ++r) {
                int p = mi * 16 + quad * 4 + r;
                stf(&states[(size_t)bch * 8192 + p * 128 + n], acc[mi][ni][r]);
            }
    }
}

// Inter-chunk scan (in place), 4 states/thread, fp32 carry.
__global__ void scan_kernel(const float* __restrict__ Acum,
                            bf16* __restrict__ states) {
    int i = blockIdx.x * 256 + threadIdx.x;     // BATCH*NHEADS*2048 exactly
    int pn0 = (i & 2047) * 4;
    int bh = i >> 11;
    int h = bh & 31, b = bh >> 5;
    float carry[4] = {0.f, 0.f, 0.f, 0.f};
    for (int c = 0; c < NCHUNK; ++c) {
        int bch = (b * NCHUNK + c) * NHEADS + h;
        bf16* sp = &states[(size_t)bch * 8192 + pn0];
        uint2 v = *(const uint2*)sp;
        float s0 = bfbits2f((unsigned short)(v.x & 0xffff));
        float s1 = bfbits2f((unsigned short)(v.x >> 16));
        float s2 = bfbits2f((unsigned short)(v.y & 0xffff));
        float s3 = bfbits2f((unsigned short)(v.y >> 16));
        uint2 o;
        o.x = (unsigned)bfbits(carry[0]) | ((unsigned)bfbits(carry[1]) << 16);
        o.y = (unsigned)bfbits(carry[2]) | ((unsigned)bfbits(carry[3]) << 16);
        *(uint2*)sp = o;
        float dec = expf(Acum[(size_t)bch * 64 + 63]);
        carry[0] = carry[0] * dec + s0;
        carry[1] = carry[1] * dec + s1;
        carry[2] = carry[2] * dec + s2;
        carry[3] = carry[3] * dec + s3;
    }
}

// ---------------------------------------------------------------------------
// MFMA Y: Y[l][p] = sum_s M[l][s]*x[s][p] + sum_n (C[l][n]*sdo[l])*state[p][n]
//                  + D[h]*x[l][p].   One wave per (b,c,h).
// ---------------------------------------------------------------------------
__global__ __launch_bounds__(64) void y_mfma_kernel(const bf16* __restrict__ xBC,
                                                    const float* __restrict__ dtb,
                                                    const float* __restrict__ Acum,
                                                    const float* __restrict__ Gbuf,
                                                    const bf16* __restrict__ states,
                                                    const float* __restrict__ Dv,
                                                    bf16* __restrict__ y) {
    __shared__ __align__(16) __bf16 Mm[64 * 72];
    __shared__ __align__(16) __bf16 xsT[64 * 72];
    __shared__ float acs[64], dtss[64], sdos[64];
    int bch = blockIdx.x;
    int h = bch & 31, bc = bch >> 5;
    int c = bc & 63, b = bc >> 6;
    int row0 = b * SEQ + c * CHUNK;
    int lane = threadIdx.x;
    int quad = lane >> 4, l16 = lane & 15;

    {
        float a = Acum[(size_t)bch * 64 + lane];
        acs[lane] = a;
        sdos[lane] = expf(a);
        dtss[lane] = dtb[(size_t)(row0 + lane) * NHEADS + h];
    }
    __syncthreads();
    for (int l = 0; l < 64; ++l) {
        int s = lane;
        float d = acs[l] - acs[s];
        float g = (s <= l) ? Gbuf[(size_t)bc * 4096 + l * 64 + s] * dtss[s] : 0.f;
        float coef = g * expf((s <= l) ? d : 0.f);
        Mm[l * 72 + s] = tobf(coef);
    }
    for (int it = 0; it < 32; ++it) {
        int l = 2 * it + (lane >> 5);
        int p0 = (lane & 31) * 2;
        unsigned v = *(const unsigned*)&xBC[(size_t)(row0 + l) * CONV_CH + h * 64 + p0];
        *(unsigned short*)&xsT[(p0    ) * 72 + l] = (unsigned short)(v & 0xffff);
        *(unsigned short*)&xsT[(p0 + 1) * 72 + l] = (unsigned short)(v >> 16);
    }
    __syncthreads();

    f32x4_t acc[4][4];
#pragma unroll
    for (int i = 0; i < 4; ++i)
#pragma unroll
        for (int j = 0; j < 4; ++j) acc[i][j] = (f32x4_t){0.f, 0.f, 0.f, 0.f};

#pragma unroll
    for (int ks = 0; ks < 2; ++ks) {
        bf16x8_t a[4], bb[4];
#pragma unroll
        for (int mi = 0; mi < 4; ++mi)
            a[mi] = *(const bf16x8_t*)(&Mm[(mi * 16 + l16) * 72 + ks * 32 + quad * 8]);
#pragma unroll
        for (int ni = 0; ni < 4; ++ni)
            bb[ni] = *(const bf16x8_t*)(&xsT[(ni * 16 + l16) * 72 + ks * 32 + quad * 8]);
#pragma unroll
        for (int mi = 0; mi < 4; ++mi)
#pragma unroll
            for (int ni = 0; ni < 4; ++ni)
                acc[mi][ni] = __builtin_amdgcn_mfma_f32_16x16x32_bf16(
                    a[mi], bb[ni], acc[mi][ni], 0, 0, 0);
    }
    float sdo_mi[4];
#pragma unroll
    for (int mi = 0; mi < 4; ++mi) sdo_mi[mi] = sdos[mi * 16 + l16];
#pragma unroll
    for (int ks = 0; ks < 4; ++ks) {
        bf16x8_t a[4], bb[4];
#pragma unroll
        for (int mi = 0; mi < 4; ++mi) {
            const unsigned* cp = (const unsigned*)&xBC[(size_t)(row0 + mi * 16 + l16) * CONV_CH
                                                       + D_INNER + D_STATE + ks * 32 + quad * 8];
            float sc = sdo_mi[mi];
#pragma unroll
            for (int jj = 0; jj < 4; ++jj) {
                unsigned v = cp[jj];
                a[mi][2 * jj    ] = tobf(bfbits2f((unsigned short)(v & 0xffff)) * sc);
                a[mi][2 * jj + 1] = tobf(bfbits2f((unsigned short)(v >> 16)) * sc);
            }
        }
#pragma unroll
        for (int ni = 0; ni < 4; ++ni)
            bb[ni] = *(const bf16x8_t*)&states[(size_t)bch * 8192 + (ni * 16 + l16) * 128
                                               + ks * 32 + quad * 8];
#pragma unroll
        for (int mi = 0; mi < 4; ++mi)
#pragma unroll
            for (int ni = 0; ni < 4; ++ni)
                acc[mi][ni] = __builtin_amdgcn_mfma_f32_16x16x32_bf16(
                    a[mi], bb[ni], acc[mi][ni], 0, 0, 0);
    }
    float Dh = Dv[h];
#pragma unroll
    for (int ni = 0; ni < 4; ++ni) {
        int p = ni * 16 + l16;
#pragma unroll
        for (int mi = 0; mi < 4; ++mi)
#pragma unroll
            for (int r = 0; r < 4; ++r) {
                int l = mi * 16 + quad * 4 + r;
                float xv = bfbits2f(*(const unsigned short*)&xsT[p * 72 + l]);
                stf(&y[(size_t)(row0 + l) * D_INNER + h * 64 + p],
                    acc[mi][ni][r] + Dh * xv);
            }
    }
}

// Per row: v = y * silu(z); y = v * rsqrt(mean(v^2)+eps) * norm_w.
__global__ __launch_bounds__(256) void gate_norm_kernel(const bf16* __restrict__ Z,
                                                        const float* __restrict__ nw,
                                                        bf16* __restrict__ y) {
    int row = blockIdx.x;
    int tid = threadIdx.x;
    int col0 = tid * 8;
    uint4 zv = *(const uint4*)&Z[(size_t)row * D_INNER + col0];
    uint4 yv = *(const uint4*)&y[(size_t)row * D_INNER + col0];
    const unsigned zz[4] = {zv.x, zv.y, zv.z, zv.w};
    const unsigned yy[4] = {yv.x, yv.y, yv.z, yv.w};
    float vals[8];
    float local = 0.f;
#pragma unroll
    for (int j = 0; j < 4; ++j) {
        float z0 = bfbits2f((unsigned short)(zz[j] & 0xffff));
        float z1 = bfbits2f((unsigned short)(zz[j] >> 16));
        float y0 = bfbits2f((unsigned short)(yy[j] & 0xffff));
        float y1 = bfbits2f((unsigned short)(yy[j] >> 16));
        float v0 = y0 * siluf_(z0);
        float v1 = y1 * siluf_(z1);
        vals[2*j] = v0; vals[2*j+1] = v1;
        local += v0 * v0 + v1 * v1;
    }
#pragma unroll
    for (int off = 32; off; off >>= 1) local += __shfl_down(local, off, 64);
    __shared__ float wsum[4];
    if ((tid & 63) == 0) wsum[tid >> 6] = local;
    __syncthreads();
    float total = wsum[0] + wsum[1] + wsum[2] + wsum[3];
    float scale = rsqrtf(total / (float)D_INNER + EPS_RMS);
    float4 w0 = ((const float4*)nw)[col0 / 4];
    float4 w1 = ((const float4*)nw)[col0 / 4 + 1];
    const float ww[8] = {w0.x, w0.y, w0.z, w0.w, w1.x, w1.y, w1.z, w1.w};
    unsigned o[4];
#pragma unroll
    for (int j = 0; j < 4; ++j)
        o[j] = (unsigned)bfbits(vals[2*j] * scale * ww[2*j]) |
               ((unsigned)bfbits(vals[2*j+1] * scale * ww[2*j+1]) << 16);
    *(uint4*)&y[(size_t)row * D_INNER + col0] = make_uint4(o[0], o[1], o[2], o[3]);
}

// ---------------------------------------------------------------------------
extern "C" void kernel_launch(void* const* d_in, const int* in_sizes, int n_in,
                              void* d_out, int out_size, void* d_ws, size_t ws_size,
                              hipStream_t stream) {
    const float* u       = (const float*)d_in[0];
    const float* W_in    = (const float*)d_in[1];
    const float* conv_w  = (const float*)d_in[2];
    const float* conv_b  = (const float*)d_in[3];
    const float* dt_bias = (const float*)d_in[4];
    const float* A_log   = (const float*)d_in[5];
    const float* Dv      = (const float*)d_in[6];
    const float* norm_w  = (const float*)d_in[7];
    const float* W_out   = (const float*)d_in[8];
    float* out = (float*)d_out;

    const size_t sz_xBC    = (size_t)ROWS * CONV_CH * 2;
    const size_t sz_Z      = (size_t)ROWS * D_INNER * 2;
    const size_t sz_y      = (size_t)ROWS * D_INNER * 2;
    const size_t sz_states = (size_t)BATCH * NCHUNK * NHEADS * 8192 * 2;  // 67.1 MB
    const size_t sz_dtb    = (size_t)ROWS * NHEADS * 4;
    const size_t sz_Acum   = (size_t)BATCH * NCHUNK * NHEADS * 64 * 4;
    const size_t sz_Gbuf   = (size_t)BATCH * NCHUNK * 4096 * 4;
    const size_t sz_WinT   = (size_t)WINT_ROWS * D_MODEL * 2;
    const size_t sz_WoutT  = (size_t)D_MODEL * D_INNER * 2;
    const size_t sz_Wc     = (size_t)CONV_CH * 4 * 2;
    const size_t need = sz_xBC + sz_Z + sz_y + sz_states + sz_dtb + sz_Acum +
                        sz_Gbuf + sz_WinT + sz_WoutT + sz_Wc;
    if (ws_size < need) {
        hipMemsetAsync(d_out, 0, (size_t)out_size * sizeof(float), stream);
        return;
    }
    char* ws = (char*)d_ws;
    size_t off = 0;
    bf16*  xBC    = (bf16*) (ws + off); off += sz_xBC;
    bf16*  Z      = (bf16*) (ws + off); off += sz_Z;
    bf16*  y      = (bf16*) (ws + off); off += sz_y;
    bf16*  states = (bf16*) (ws + off); off += sz_states;
    float* dtb    = (float*)(ws + off); off += sz_dtb;
    float* Acum   = (float*)(ws + off); off += sz_Acum;
    float* Gbuf   = (float*)(ws + off); off += sz_Gbuf;
    bf16*  W_inT  = (bf16*) (ws + off); off += sz_WinT;
    bf16*  W_outT = (bf16*) (ws + off); off += sz_WoutT;
    bf16*  Wc     = (bf16*) (ws + off); off += sz_Wc;
    // Aliases of the states region (67.1 MB), all dead before their overwrite:
    //  - R (38.3 MB) + u_bf16 (16.8 MB): dead before states_mfma_kernel.
    //  - out_part (2 x 33.55 MB fp32 = 67.1 MB): written after gate_norm,
    //    when states is dead (last read: y_mfma_kernel).
    bf16*  R        = states;
    bf16*  u_bf16   = (bf16*)((char*)states + (size_t)ROWS * RCOLS * 2);
    float* out_part = (float*)states;

    // 0) prep
    cvt_bf16_kernel<<<(ROWS * D_MODEL / 4 + 255) / 256, 256, 0, stream>>>(
        u, u_bf16, ROWS * D_MODEL / 4);
    transpose_cvt_kernel<<<dim3(WINT_ROWS / 32, D_MODEL / 32), 256, 0, stream>>>(
        W_in, W_inT, D_MODEL, D_IN_PROJ, WINT_ROWS);
    transpose_cvt_kernel<<<dim3(D_MODEL / 32, D_INNER / 32), 256, 0, stream>>>(
        W_out, W_outT, D_INNER, D_MODEL, D_MODEL);
    prep_convw_kernel<<<(CONV_CH * 4 + 255) / 256, 256, 0, stream>>>(conv_w, Wc);
    // 1) fused Z|R GEMM: one dispatch, 64x35 = 2240 blocks (~8.75/CU)
    gemm_zr_fused<<<dim3(ROWS / 128, 35), 256, 0, stream>>>(u_bf16, W_inT, Z, R);
    // 2) conv + silu (4 rows/thread) ; dt
    conv_silu_kernel<<<ROWS / 4 * 288 / 256, 256, 0, stream>>>(R, Wc, conv_b, xBC);
    dt_kernel<<<ROWS * 4 / 256, 256, 0, stream>>>(R, dt_bias, dtb);
    // 3) per-chunk cumsum of A*dt
    acum_kernel<<<BATCH * NCHUNK * NHEADS, 64, 0, stream>>>(dtb, A_log, Acum);
    // 4) G = C @ B^T per (b,c)  (MFMA)
    gchunk_mfma_kernel<<<BATCH * NCHUNK, 64, 0, stream>>>(xBC, Gbuf);
    // 5) per-chunk states (MFMA; overwrites R/u_bf16 aliases — both dead)
    states_mfma_kernel<<<BATCH * NCHUNK * 8, 256, 0, stream>>>(xBC, dtb, Acum, states);
    // 6) inter-chunk scan (4 elems/thread)
    scan_kernel<<<BATCH * NHEADS * 2048 / 256, 256, 0, stream>>>(Acum, states);
    // 7+8) Y = diag + off + D*x  (MFMA, fused)
    y_mfma_kernel<<<BATCH * NCHUNK * NHEADS, 64, 0, stream>>>(
        xBC, dtb, Acum, Gbuf, states, Dv, y);
    // 9) gate + RMSNorm
    gate_norm_kernel<<<ROWS, 256, 0, stream>>>(Z, norm_w, y);
    // 10) out = y @ W_out, split-K=2 (partials overwrite dead states region)
    gemm_out_splitk<<<dim3(ROWS / 128, D_MODEL / 128, 2), 256, 0, stream>>>(
        y, W_outT, out_part);
    reduce_out_kernel<<<ROWS * D_MODEL / 4 / 256, 256, 0, stream>>>(out_part, out);
}